// Round 8
// baseline (405.943 us; speedup 1.0000x reference)
//
#include <hip/hip_runtime.h>
#include <math.h>

#define D_MODEL 256
#define NHEAD   8
#define NLVL    4
#define NPTS    4
#define DHEAD   32
#define DFFN    1024
#define NQ      900
#define BSZ     4
#define NROW    (NQ * BSZ)      // 3600
#define S_TOT   11253
#define VROWS   (S_TOT * BSZ)   // 45012
#define SASCALE 0.17677669529663687f

typedef __attribute__((ext_vector_type(8))) short short8;
typedef __attribute__((ext_vector_type(4))) float f32x4;
typedef unsigned short ushort_t;

static __device__ __forceinline__ unsigned f2bf1(float f) {
    unsigned u = __float_as_uint(f);
    return (u + 0x7FFFu + ((u >> 16) & 1u)) >> 16;
}
static __device__ __forceinline__ unsigned pack2bf(float x, float y) {
    return f2bf1(x) | (f2bf1(y) << 16);
}
static __device__ __forceinline__ float bf2f(ushort_t u) {
    return __uint_as_float(((unsigned)u) << 16);
}

#define GPAD 72

// ---------------------------------------------------------------------------
// proj_fused: qkv projection (blocks 0..683) + value projection (684..1387).
// Both paths are the proven R4/R7 kernels, merged to save a dispatch and
// overlap execution (they are independent).
// ---------------------------------------------------------------------------
__global__ __launch_bounds__(256) void proj_fused(
    const float* __restrict__ tgt, const float* __restrict__ qpos,
    const float* __restrict__ in_w, const float* __restrict__ in_b,
    const float* __restrict__ mem, const float* __restrict__ vp_w,
    const float* __restrict__ vp_b,
    ushort_t* __restrict__ qkv16, ushort_t* __restrict__ value16)
{
    __shared__ ushort_t As[64 * GPAD];
    __shared__ ushort_t Ws[256 * GPAD];

    const int t    = threadIdx.x;
    const int bid  = blockIdx.x;
    const int trow = t >> 2;
    const int tk   = (t & 3) << 4;
    const int wv   = t >> 6;
    const int ln   = t & 63;
    const int L    = ln & 15;
    const int quad = ln >> 4;

    if (bid < 684) {
        // ---------------- QKV path ----------------
        const int m0 = (bid % 57) * 64;
        const int n0 = (bid / 57) * 64;
        const bool addpos = (n0 < 512);
        const float oscale = (n0 < 256) ? SASCALE : 1.f;

        f32x4 acc[4] = {{0.f,0.f,0.f,0.f},{0.f,0.f,0.f,0.f},
                        {0.f,0.f,0.f,0.f},{0.f,0.f,0.f,0.f}};

        for (int k0 = 0; k0 < 256; k0 += 64) {
            {
                int m = m0 + trow;
                float4 a0, a1, a2, a3;
                if (m < NROW) {
                    const float* ap = tgt + (size_t)m * 256 + k0 + tk;
                    a0 = *(const float4*)(ap + 0);
                    a1 = *(const float4*)(ap + 4);
                    a2 = *(const float4*)(ap + 8);
                    a3 = *(const float4*)(ap + 12);
                    if (addpos) {
                        const float* pp = qpos + (size_t)m * 256 + k0 + tk;
                        float4 p0 = *(const float4*)(pp + 0);
                        float4 p1 = *(const float4*)(pp + 4);
                        float4 p2 = *(const float4*)(pp + 8);
                        float4 p3 = *(const float4*)(pp + 12);
                        a0.x += p0.x; a0.y += p0.y; a0.z += p0.z; a0.w += p0.w;
                        a1.x += p1.x; a1.y += p1.y; a1.z += p1.z; a1.w += p1.w;
                        a2.x += p2.x; a2.y += p2.y; a2.z += p2.z; a2.w += p2.w;
                        a3.x += p3.x; a3.y += p3.y; a3.z += p3.z; a3.w += p3.w;
                    }
                } else {
                    a0 = a1 = a2 = a3 = make_float4(0.f, 0.f, 0.f, 0.f);
                }
                uint4 u0, u1;
                u0.x = pack2bf(a0.x, a0.y); u0.y = pack2bf(a0.z, a0.w);
                u0.z = pack2bf(a1.x, a1.y); u0.w = pack2bf(a1.z, a1.w);
                u1.x = pack2bf(a2.x, a2.y); u1.y = pack2bf(a2.z, a2.w);
                u1.z = pack2bf(a3.x, a3.y); u1.w = pack2bf(a3.z, a3.w);
                *(uint4*)&As[trow * GPAD + tk + 0] = u0;
                *(uint4*)&As[trow * GPAD + tk + 8] = u1;
            }
            {
                int n = n0 + trow;
                const float* wp = in_w + (size_t)n * 256 + k0 + tk;
                float4 a0 = *(const float4*)(wp + 0);
                float4 a1 = *(const float4*)(wp + 4);
                float4 a2 = *(const float4*)(wp + 8);
                float4 a3 = *(const float4*)(wp + 12);
                uint4 u0, u1;
                u0.x = pack2bf(a0.x, a0.y); u0.y = pack2bf(a0.z, a0.w);
                u0.z = pack2bf(a1.x, a1.y); u0.w = pack2bf(a1.z, a1.w);
                u1.x = pack2bf(a2.x, a2.y); u1.y = pack2bf(a2.z, a2.w);
                u1.z = pack2bf(a3.x, a3.y); u1.w = pack2bf(a3.z, a3.w);
                *(uint4*)&Ws[trow * GPAD + tk + 0] = u0;
                *(uint4*)&Ws[trow * GPAD + tk + 8] = u1;
            }
            __syncthreads();
#pragma unroll
            for (int kh = 0; kh < 2; ++kh) {
                short8 af = *(const short8*)&As[(wv * 16 + L) * GPAD + kh * 32 + quad * 8];
#pragma unroll
                for (int cb = 0; cb < 4; ++cb) {
                    short8 bf = *(const short8*)&Ws[(cb * 16 + L) * GPAD + kh * 32 + quad * 8];
                    acc[cb] = __builtin_amdgcn_mfma_f32_16x16x32_bf16(af, bf, acc[cb], 0, 0, 0);
                }
            }
            __syncthreads();
        }
#pragma unroll
        for (int cb = 0; cb < 4; ++cb) {
            int col = n0 + cb * 16 + L;
            float bv = in_b[col];
#pragma unroll
            for (int i = 0; i < 4; ++i) {
                int m = m0 + wv * 16 + quad * 4 + i;
                if (m < NROW)
                    qkv16[(size_t)m * 768 + col] = (ushort_t)f2bf1((acc[cb][i] + bv) * oscale);
            }
        }
    } else {
        // ---------------- value-projection path ----------------
        const int m0 = (bid - 684) * 64;

        f32x4 acc[16];
#pragma unroll
        for (int i = 0; i < 16; ++i) acc[i] = (f32x4){0.f, 0.f, 0.f, 0.f};

        for (int k0 = 0; k0 < 256; k0 += 64) {
            {
                int m = m0 + trow;
                float4 a0, a1, a2, a3;
                if (m < VROWS) {
                    const float* ap = mem + (size_t)m * 256 + k0 + tk;
                    a0 = *(const float4*)(ap + 0);
                    a1 = *(const float4*)(ap + 4);
                    a2 = *(const float4*)(ap + 8);
                    a3 = *(const float4*)(ap + 12);
                } else {
                    a0 = a1 = a2 = a3 = make_float4(0.f, 0.f, 0.f, 0.f);
                }
                uint4 u0, u1;
                u0.x = pack2bf(a0.x, a0.y); u0.y = pack2bf(a0.z, a0.w);
                u0.z = pack2bf(a1.x, a1.y); u0.w = pack2bf(a1.z, a1.w);
                u1.x = pack2bf(a2.x, a2.y); u1.y = pack2bf(a2.z, a2.w);
                u1.z = pack2bf(a3.x, a3.y); u1.w = pack2bf(a3.z, a3.w);
                *(uint4*)&As[trow * GPAD + tk + 0] = u0;
                *(uint4*)&As[trow * GPAD + tk + 8] = u1;
            }
#pragma unroll
            for (int wb = 0; wb < 4; ++wb) {
                int n = wb * 64 + trow;
                const float* wp = vp_w + (size_t)n * 256 + k0 + tk;
                float4 a0 = *(const float4*)(wp + 0);
                float4 a1 = *(const float4*)(wp + 4);
                float4 a2 = *(const float4*)(wp + 8);
                float4 a3 = *(const float4*)(wp + 12);
                uint4 u0, u1;
                u0.x = pack2bf(a0.x, a0.y); u0.y = pack2bf(a0.z, a0.w);
                u0.z = pack2bf(a1.x, a1.y); u0.w = pack2bf(a1.z, a1.w);
                u1.x = pack2bf(a2.x, a2.y); u1.y = pack2bf(a2.z, a2.w);
                u1.z = pack2bf(a3.x, a3.y); u1.w = pack2bf(a3.z, a3.w);
                *(uint4*)&Ws[n * GPAD + tk + 0] = u0;
                *(uint4*)&Ws[n * GPAD + tk + 8] = u1;
            }
            __syncthreads();
#pragma unroll
            for (int kh = 0; kh < 2; ++kh) {
                short8 af = *(const short8*)&As[(wv * 16 + L) * GPAD + kh * 32 + quad * 8];
#pragma unroll
                for (int cb = 0; cb < 16; ++cb) {
                    short8 bf = *(const short8*)&Ws[(cb * 16 + L) * GPAD + kh * 32 + quad * 8];
                    acc[cb] = __builtin_amdgcn_mfma_f32_16x16x32_bf16(af, bf, acc[cb], 0, 0, 0);
                }
            }
            __syncthreads();
        }

        ushort_t* Cs = Ws;
#pragma unroll
        for (int cb = 0; cb < 16; ++cb) {
            int col = cb * 16 + L;
            float bv = vp_b[col];
#pragma unroll
            for (int i = 0; i < 4; ++i) {
                int r = wv * 16 + quad * 4 + i;
                Cs[r * 264 + col] = (ushort_t)f2bf1(acc[cb][i] + bv);
            }
        }
        __syncthreads();
        {
            int r  = t >> 2;
            int ch = (t & 3) * 64;
            int m  = m0 + r;
            if (m < VROWS) {
                const ushort_t* src = &Cs[r * 264 + ch];
                uint4* dst = (uint4*)(value16 + (size_t)m * 256 + ch);
#pragma unroll
                for (int j = 0; j < 8; ++j)
                    dst[j] = *(const uint4*)(src + j * 8);
            }
        }
    }
}

// ---------------------------------------------------------------------------
// MFMA flash self-attention, bf16 in / bf16 out (unchanged).
// ---------------------------------------------------------------------------
__global__ __launch_bounds__(256) void sa_flash16(
    const ushort_t* __restrict__ qkv, ushort_t* __restrict__ attn_out)
{
    __shared__ ushort_t Ks[2 * 2080];
    __shared__ ushort_t Vt[2 * 2304];
    __shared__ ushort_t Ps[4 * 1152];

    const int t    = threadIdx.x;
    const int q0   = blockIdx.x * 64;
    const int b    = blockIdx.y & 3;
    const int h    = blockIdx.y >> 2;
    const int wv   = t >> 6;
    const int ln   = t & 63;
    const int L    = ln & 15;
    const int quad = ln >> 4;

    union { uint4 u; short8 s; } qu;
    qu.u = make_uint4(0u, 0u, 0u, 0u);
    {
        int q = q0 + wv * 16 + L;
        if (q < NQ)
            qu.u = *(const uint4*)(qkv + ((size_t)q * 4 + b) * 768 + h * 32 + quad * 8);
    }
    const short8 qf = qu.s;

    float mrun = -1e30f, lrun = 0.f;
    f32x4 oacc[2] = {{0.f,0.f,0.f,0.f},{0.f,0.f,0.f,0.f}};

    const int skey = t >> 2;
    const int sdg  = t & 3;

    int it = 0;
    for (int k0 = 0; k0 < NQ; k0 += 64, it ^= 1) {
        {
            int kg = k0 + skey;
            uint4 ku = make_uint4(0u,0u,0u,0u), vu = make_uint4(0u,0u,0u,0u);
            if (kg < NQ) {
                const ushort_t* base = qkv + ((size_t)kg * 4 + b) * 768 + 256 + h * 32 + sdg * 8;
                ku = *(const uint4*)base;
                vu = *(const uint4*)(base + 256);
            }
            *(uint4*)&Ks[it * 2080 + sdg * 520 + skey * 8] = ku;
            ushort_t* vp = &Vt[it * 2304 + sdg * 8 * 72 + skey];
            vp[0 * 72] = (ushort_t)(vu.x & 0xffffu);
            vp[1 * 72] = (ushort_t)(vu.x >> 16);
            vp[2 * 72] = (ushort_t)(vu.y & 0xffffu);
            vp[3 * 72] = (ushort_t)(vu.y >> 16);
            vp[4 * 72] = (ushort_t)(vu.z & 0xffffu);
            vp[5 * 72] = (ushort_t)(vu.z >> 16);
            vp[6 * 72] = (ushort_t)(vu.w & 0xffffu);
            vp[7 * 72] = (ushort_t)(vu.w >> 16);
        }
        __syncthreads();

        f32x4 sacc[4] = {{0.f,0.f,0.f,0.f},{0.f,0.f,0.f,0.f},
                         {0.f,0.f,0.f,0.f},{0.f,0.f,0.f,0.f}};
#pragma unroll
        for (int cb = 0; cb < 4; ++cb) {
            short8 kf = *(const short8*)&Ks[it * 2080 + quad * 520 + (cb * 16 + L) * 8];
            sacc[cb] = __builtin_amdgcn_mfma_f32_16x16x32_bf16(kf, qf, sacc[cb], 0, 0, 0);
        }
        if (k0 + 64 > NQ) {
#pragma unroll
            for (int cb = 0; cb < 4; ++cb)
#pragma unroll
                for (int i = 0; i < 4; ++i)
                    if (k0 + cb * 16 + quad * 4 + i >= NQ) sacc[cb][i] = -1e30f;
        }

        float ml = -1e30f;
#pragma unroll
        for (int cb = 0; cb < 4; ++cb)
#pragma unroll
            for (int i = 0; i < 4; ++i) ml = fmaxf(ml, sacc[cb][i]);
        ml = fmaxf(ml, __shfl_xor(ml, 16, 64));
        ml = fmaxf(ml, __shfl_xor(ml, 32, 64));
        float mnew  = fmaxf(mrun, ml);
        float alpha = __expf(mrun - mnew);
        float p[16];
        float rs = 0.f;
#pragma unroll
        for (int cb = 0; cb < 4; ++cb)
#pragma unroll
            for (int i = 0; i < 4; ++i) {
                float e = __expf(sacc[cb][i] - mnew);
                p[cb * 4 + i] = e;
                rs += e;
            }
        rs += __shfl_xor(rs, 16, 64);
        rs += __shfl_xor(rs, 32, 64);
        lrun = lrun * alpha + rs;
        mrun = mnew;

        {
            ushort_t* pw = &Ps[wv * 1152 + L * 72];
#pragma unroll
            for (int cb = 0; cb < 4; ++cb) {
                uint2 u;
                u.x = pack2bf(p[cb * 4 + 0], p[cb * 4 + 1]);
                u.y = pack2bf(p[cb * 4 + 2], p[cb * 4 + 3]);
                *(uint2*)&pw[cb * 16 + quad * 4] = u;
            }
        }
#pragma unroll
        for (int i = 0; i < 4; ++i) {
            float ai = __shfl(alpha, quad * 4 + i, 64);
            oacc[0][i] *= ai;
            oacc[1][i] *= ai;
        }
        __syncthreads();

#pragma unroll
        for (int ks = 0; ks < 2; ++ks) {
            short8 pf = *(const short8*)&Ps[wv * 1152 + L * 72 + ks * 32 + quad * 8];
#pragma unroll
            for (int db = 0; db < 2; ++db) {
                short8 vf = *(const short8*)&Vt[it * 2304 + (db * 16 + L) * 72 + ks * 32 + quad * 8];
                oacc[db] = __builtin_amdgcn_mfma_f32_16x16x32_bf16(pf, vf, oacc[db], 0, 0, 0);
            }
        }
    }

#pragma unroll
    for (int i = 0; i < 4; ++i) {
        float lq = __shfl(lrun, quad * 4 + i, 64);
        float li = 1.f / lq;
        int q = q0 + wv * 16 + quad * 4 + i;
        if (q < NQ) {
            ushort_t* op = attn_out + ((size_t)q * 4 + b) * 256 + h * 32 + L;
            op[0]  = (ushort_t)f2bf1(oacc[0][i] * li);
            op[16] = (ushort_t)f2bf1(oacc[1][i] * li);
        }
    }
}

// ---------------------------------------------------------------------------
// Plain 64x64-tile GEMM, bf16 A, fp32 W, fp32 C (proven-fast, unchanged).
// ---------------------------------------------------------------------------
__global__ __launch_bounds__(256) void gemm16_f32(
    const ushort_t* __restrict__ A, const float* __restrict__ W,
    const float* __restrict__ bias, float* __restrict__ C,
    int M, int N, int K, int ldc)
{
    __shared__ ushort_t As[64 * GPAD];
    __shared__ ushort_t Ws[64 * GPAD];

    const int t  = threadIdx.x;
    const int m0 = blockIdx.x * 64;
    const int n0 = blockIdx.y * 64;
    const int trow = t >> 2;
    const int tk   = (t & 3) << 4;
    const int wv   = t >> 6;
    const int ln   = t & 63;
    const int L    = ln & 15;
    const int quad = ln >> 4;

    f32x4 acc[4] = {{0.f,0.f,0.f,0.f},{0.f,0.f,0.f,0.f},
                    {0.f,0.f,0.f,0.f},{0.f,0.f,0.f,0.f}};

    for (int k0 = 0; k0 < K; k0 += 64) {
        {
            int m = m0 + trow;
            uint4 a0 = make_uint4(0u,0u,0u,0u), a1 = make_uint4(0u,0u,0u,0u);
            if (m < M) {
                const ushort_t* ap = A + (size_t)m * K + k0 + tk;
                a0 = *(const uint4*)ap;
                a1 = *(const uint4*)(ap + 8);
            }
            *(uint4*)&As[trow * GPAD + tk + 0] = a0;
            *(uint4*)&As[trow * GPAD + tk + 8] = a1;
        }
        {
            int n = n0 + trow;
            const float* wp = W + (size_t)n * K + k0 + tk;
            float4 a0 = *(const float4*)(wp + 0);
            float4 a1 = *(const float4*)(wp + 4);
            float4 a2 = *(const float4*)(wp + 8);
            float4 a3 = *(const float4*)(wp + 12);
            uint4 u0, u1;
            u0.x = pack2bf(a0.x, a0.y); u0.y = pack2bf(a0.z, a0.w);
            u0.z = pack2bf(a1.x, a1.y); u0.w = pack2bf(a1.z, a1.w);
            u1.x = pack2bf(a2.x, a2.y); u1.y = pack2bf(a2.z, a2.w);
            u1.z = pack2bf(a3.x, a3.y); u1.w = pack2bf(a3.z, a3.w);
            *(uint4*)&Ws[trow * GPAD + tk + 0] = u0;
            *(uint4*)&Ws[trow * GPAD + tk + 8] = u1;
        }
        __syncthreads();
#pragma unroll
        for (int kh = 0; kh < 2; ++kh) {
            short8 af = *(const short8*)&As[(wv * 16 + L) * GPAD + kh * 32 + quad * 8];
#pragma unroll
            for (int cb = 0; cb < 4; ++cb) {
                short8 bf = *(const short8*)&Ws[(cb * 16 + L) * GPAD + kh * 32 + quad * 8];
                acc[cb] = __builtin_amdgcn_mfma_f32_16x16x32_bf16(af, bf, acc[cb], 0, 0, 0);
            }
        }
        __syncthreads();
    }
#pragma unroll
    for (int cb = 0; cb < 4; ++cb) {
        int col = n0 + cb * 16 + L;
        float bv = bias[col];
#pragma unroll
        for (int i = 0; i < 4; ++i) {
            int m = m0 + wv * 16 + quad * 4 + i;
            if (m < M)
                C[(size_t)m * ldc + col] = acc[cb][i] + bv;
        }
    }
}

// ---------------------------------------------------------------------------
// offaw_ln: LN2 fused as a prologue of the proven offaw kernel.
// x = tgt + tmp; y = LN(x)*g+b; A-frag = bf16(y + qpos) built in LDS.
// by==0 blocks also write tgt_a (fp32 y). k-loop/epilogue = proven offaw16.
// ---------------------------------------------------------------------------
__global__ __launch_bounds__(256) void offaw_ln(
    const float* __restrict__ tgt, const float* __restrict__ tmp,
    const float* __restrict__ qpos,
    const float* __restrict__ gam, const float* __restrict__ bet,
    const float* __restrict__ off_w, const float* __restrict__ off_b,
    const float* __restrict__ aw_w, const float* __restrict__ aw_b,
    float* __restrict__ off_raw, float* __restrict__ aw_raw,
    float* __restrict__ tgt_a)
{
    __shared__ ushort_t Axc[4][64 * GPAD];   // 4 k-chunks, proven As layout
    __shared__ ushort_t Ws[64 * GPAD];

    const int t  = threadIdx.x;
    const int m0 = blockIdx.x * 64;
    const int by = blockIdx.y;
    const bool isaw = (by >= 4);
    const int n0 = isaw ? (by - 4) * 64 : by * 64;
    const float* W  = isaw ? aw_w : off_w;
    const float* bs = isaw ? aw_b : off_b;
    float* C = isaw ? aw_raw : off_raw;
    const int ldc = isaw ? 128 : 256;

    const int wv   = t >> 6;
    const int ln   = t & 63;
    const int L    = ln & 15;
    const int quad = ln >> 4;
    const int trow = t >> 2;
    const int tk   = (t & 3) << 4;

    // ---- prologue: residual + LN2, 4 threads per row ----
    {
        const int row = t >> 2, c4 = t & 3;
        const int m = m0 + row;
        const size_t base = (size_t)m * 256 + c4 * 64;
        float s = 0.f, s2 = 0.f;
        if (m < NROW) {
#pragma unroll
            for (int seg = 0; seg < 16; ++seg) {
                float4 a = *(const float4*)(tgt + base + seg * 4);
                float4 b = *(const float4*)(tmp + base + seg * 4);
                float x0 = a.x + b.x, x1 = a.y + b.y;
                float x2 = a.z + b.z, x3 = a.w + b.w;
                s  += x0 + x1 + x2 + x3;
                s2 += x0*x0 + x1*x1 + x2*x2 + x3*x3;
            }
        }
        s  += __shfl_xor(s, 1, 64);  s  += __shfl_xor(s, 2, 64);
        s2 += __shfl_xor(s2, 1, 64); s2 += __shfl_xor(s2, 2, 64);
        float mean = s * (1.f / 256.f);
        float var  = s2 * (1.f / 256.f) - mean * mean;
        float rstd = rsqrtf(var + 1e-5f);
        if (m < NROW) {
#pragma unroll
            for (int seg = 0; seg < 16; ++seg) {
                int col = c4 * 64 + seg * 4;
                float4 a = *(const float4*)(tgt + base + seg * 4);
                float4 b = *(const float4*)(tmp + base + seg * 4);
                float4 g = *(const float4*)(gam + col);
                float4 be = *(const float4*)(bet + col);
                float4 p = *(const float4*)(qpos + base + seg * 4);
                float y0 = (a.x + b.x - mean) * rstd * g.x + be.x;
                float y1 = (a.y + b.y - mean) * rstd * g.y + be.y;
                float y2 = (a.z + b.z - mean) * rstd * g.z + be.z;
                float y3 = (a.w + b.w - mean) * rstd * g.w + be.w;
                if (by == 0)
                    *(float4*)(tgt_a + base + seg * 4) = make_float4(y0, y1, y2, y3);
                uint2 u;
                u.x = pack2bf(y0 + p.x, y1 + p.y);
                u.y = pack2bf(y2 + p.z, y3 + p.w);
                *(uint2*)&Axc[c4][row * GPAD + seg * 4] = u;
            }
        } else {
#pragma unroll
            for (int seg = 0; seg < 16; ++seg)
                *(uint2*)&Axc[c4][row * GPAD + seg * 4] = make_uint2(0u, 0u);
        }
    }
    __syncthreads();

    f32x4 acc[4] = {{0.f,0.f,0.f,0.f},{0.f,0.f,0.f,0.f},
                    {0.f,0.f,0.f,0.f},{0.f,0.f,0.f,0.f}};

    for (int kc = 0; kc < 4; ++kc) {
        {
            int n = n0 + trow;
            const float* wp = W + (size_t)n * 256 + kc * 64 + tk;
            float4 a0 = *(const float4*)(wp + 0);
            float4 a1 = *(const float4*)(wp + 4);
            float4 a2 = *(const float4*)(wp + 8);
            float4 a3 = *(const float4*)(wp + 12);
            uint4 u0, u1;
            u0.x = pack2bf(a0.x, a0.y); u0.y = pack2bf(a0.z, a0.w);
            u0.z = pack2bf(a1.x, a1.y); u0.w = pack2bf(a1.z, a1.w);
            u1.x = pack2bf(a2.x, a2.y); u1.y = pack2bf(a2.z, a2.w);
            u1.z = pack2bf(a3.x, a3.y); u1.w = pack2bf(a3.z, a3.w);
            *(uint4*)&Ws[trow * GPAD + tk + 0] = u0;
            *(uint4*)&Ws[trow * GPAD + tk + 8] = u1;
        }
        __syncthreads();
#pragma unroll
        for (int kh = 0; kh < 2; ++kh) {
            short8 af = *(const short8*)&Axc[kc][(wv * 16 + L) * GPAD + kh * 32 + quad * 8];
#pragma unroll
            for (int cb = 0; cb < 4; ++cb) {
                short8 bf = *(const short8*)&Ws[(cb * 16 + L) * GPAD + kh * 32 + quad * 8];
                acc[cb] = __builtin_amdgcn_mfma_f32_16x16x32_bf16(af, bf, acc[cb], 0, 0, 0);
            }
        }
        __syncthreads();
    }
#pragma unroll
    for (int cb = 0; cb < 4; ++cb) {
        int col = n0 + cb * 16 + L;
        float bv = bs[col];
#pragma unroll
        for (int i = 0; i < 4; ++i) {
            int m = m0 + wv * 16 + quad * 4 + i;
            if (m < NROW)
                C[(size_t)m * ldc + col] = acc[cb][i] + bv;
        }
    }
}

// ---------------------------------------------------------------------------
// ffn1_ln: LN1 fused as a prologue of FFN1 (relu, bf16 out).
// x = tgt_a + tmp; y = LN(x); by==0 writes tgt_b. Grid (57, 16).
// ---------------------------------------------------------------------------
__global__ __launch_bounds__(256) void ffn1_ln(
    const float* __restrict__ tgta, const float* __restrict__ tmp,
    const float* __restrict__ gam, const float* __restrict__ bet,
    const float* __restrict__ W, const float* __restrict__ bias,
    ushort_t* __restrict__ hidden, float* __restrict__ tgt_b)
{
    __shared__ ushort_t Axc[4][64 * GPAD];
    __shared__ ushort_t Ws[64 * GPAD];

    const int t  = threadIdx.x;
    const int m0 = blockIdx.x * 64;
    const int by = blockIdx.y;
    const int n0 = by * 64;

    const int wv   = t >> 6;
    const int ln   = t & 63;
    const int L    = ln & 15;
    const int quad = ln >> 4;
    const int trow = t >> 2;
    const int tk   = (t & 3) << 4;

    {
        const int row = t >> 2, c4 = t & 3;
        const int m = m0 + row;
        const size_t base = (size_t)m * 256 + c4 * 64;
        float s = 0.f, s2 = 0.f;
        if (m < NROW) {
#pragma unroll
            for (int seg = 0; seg < 16; ++seg) {
                float4 a = *(const float4*)(tgta + base + seg * 4);
                float4 b = *(const float4*)(tmp + base + seg * 4);
                float x0 = a.x + b.x, x1 = a.y + b.y;
                float x2 = a.z + b.z, x3 = a.w + b.w;
                s  += x0 + x1 + x2 + x3;
                s2 += x0*x0 + x1*x1 + x2*x2 + x3*x3;
            }
        }
        s  += __shfl_xor(s, 1, 64);  s  += __shfl_xor(s, 2, 64);
        s2 += __shfl_xor(s2, 1, 64); s2 += __shfl_xor(s2, 2, 64);
        float mean = s * (1.f / 256.f);
        float var  = s2 * (1.f / 256.f) - mean * mean;
        float rstd = rsqrtf(var + 1e-5f);
        if (m < NROW) {
#pragma unroll
            for (int seg = 0; seg < 16; ++seg) {
                int col = c4 * 64 + seg * 4;
                float4 a = *(const float4*)(tgta + base + seg * 4);
                float4 b = *(const float4*)(tmp + base + seg * 4);
                float4 g = *(const float4*)(gam + col);
                float4 be = *(const float4*)(bet + col);
                float y0 = (a.x + b.x - mean) * rstd * g.x + be.x;
                float y1 = (a.y + b.y - mean) * rstd * g.y + be.y;
                float y2 = (a.z + b.z - mean) * rstd * g.z + be.z;
                float y3 = (a.w + b.w - mean) * rstd * g.w + be.w;
                if (by == 0)
                    *(float4*)(tgt_b + base + seg * 4) = make_float4(y0, y1, y2, y3);
                uint2 u;
                u.x = pack2bf(y0, y1);
                u.y = pack2bf(y2, y3);
                *(uint2*)&Axc[c4][row * GPAD + seg * 4] = u;
            }
        } else {
#pragma unroll
            for (int seg = 0; seg < 16; ++seg)
                *(uint2*)&Axc[c4][row * GPAD + seg * 4] = make_uint2(0u, 0u);
        }
    }
    __syncthreads();

    f32x4 acc[4] = {{0.f,0.f,0.f,0.f},{0.f,0.f,0.f,0.f},
                    {0.f,0.f,0.f,0.f},{0.f,0.f,0.f,0.f}};

    for (int kc = 0; kc < 4; ++kc) {
        {
            int n = n0 + trow;
            const float* wp = W + (size_t)n * 256 + kc * 64 + tk;
            float4 a0 = *(const float4*)(wp + 0);
            float4 a1 = *(const float4*)(wp + 4);
            float4 a2 = *(const float4*)(wp + 8);
            float4 a3 = *(const float4*)(wp + 12);
            uint4 u0, u1;
            u0.x = pack2bf(a0.x, a0.y); u0.y = pack2bf(a0.z, a0.w);
            u0.z = pack2bf(a1.x, a1.y); u0.w = pack2bf(a1.z, a1.w);
            u1.x = pack2bf(a2.x, a2.y); u1.y = pack2bf(a2.z, a2.w);
            u1.z = pack2bf(a3.x, a3.y); u1.w = pack2bf(a3.z, a3.w);
            *(uint4*)&Ws[trow * GPAD + tk + 0] = u0;
            *(uint4*)&Ws[trow * GPAD + tk + 8] = u1;
        }
        __syncthreads();
#pragma unroll
        for (int kh = 0; kh < 2; ++kh) {
            short8 af = *(const short8*)&Axc[kc][(wv * 16 + L) * GPAD + kh * 32 + quad * 8];
#pragma unroll
            for (int cb = 0; cb < 4; ++cb) {
                short8 bf = *(const short8*)&Ws[(cb * 16 + L) * GPAD + kh * 32 + quad * 8];
                acc[cb] = __builtin_amdgcn_mfma_f32_16x16x32_bf16(af, bf, acc[cb], 0, 0, 0);
            }
        }
        __syncthreads();
    }
#pragma unroll
    for (int cb = 0; cb < 4; ++cb) {
        int col = n0 + cb * 16 + L;
        float bv = bias[col];
#pragma unroll
        for (int i = 0; i < 4; ++i) {
            int m = m0 + wv * 16 + quad * 4 + i;
            if (m < NROW) {
                float o = fmaxf(acc[cb][i] + bv, 0.f);
                hidden[(size_t)m * 1024 + col] = (ushort_t)f2bf1(o);
            }
        }
    }
}

// ---------------------------------------------------------------------------
// Residual + LayerNorm standalone (LN3 -> d_out).
// ---------------------------------------------------------------------------
__global__ __launch_bounds__(256) void ln_resid16(
    const float* __restrict__ xa, const float* __restrict__ xb,
    const float* __restrict__ gam, const float* __restrict__ bet,
    float* __restrict__ out)
{
    const int row = blockIdx.x;
    const int t = threadIdx.x;
    float x = xa[(size_t)row * D_MODEL + t] + xb[(size_t)row * D_MODEL + t];
    float s = x, s2 = x * x;
#pragma unroll
    for (int off = 32; off > 0; off >>= 1) {
        s  += __shfl_down(s, off, 64);
        s2 += __shfl_down(s2, off, 64);
    }
    __shared__ float rs[4], rs2[4];
    __shared__ float mean_s, rstd_s;
    int wid = t >> 6, lane = t & 63;
    if (lane == 0) { rs[wid] = s; rs2[wid] = s2; }
    __syncthreads();
    if (t == 0) {
        float S = rs[0] + rs[1] + rs[2] + rs[3];
        float S2 = rs2[0] + rs2[1] + rs2[2] + rs2[3];
        float mean = S * (1.f / 256.f);
        float var = S2 * (1.f / 256.f) - mean * mean;
        mean_s = mean;
        rstd_s = rsqrtf(var + 1e-5f);
    }
    __syncthreads();
    out[(size_t)row * D_MODEL + t] = (x - mean_s) * rstd_s * gam[t] + bet[t];
}

// ---------------------------------------------------------------------------
// Multi-scale deformable sampling (unchanged).
// ---------------------------------------------------------------------------
__global__ __launch_bounds__(256) void msdeform16(
    const float* __restrict__ off_raw, const float* __restrict__ aw_raw,
    const float* __restrict__ refp, const ushort_t* __restrict__ value,
    ushort_t* __restrict__ out)
{
    const int row = blockIdx.x;   // q*4+b
    const int b = row & 3;
    const int t = threadIdx.x;

    __shared__ float aw_s[8][17];
    __shared__ float px_s[8][16];
    __shared__ float py_s[8][16];

    const int Hs[4]  = {92, 46, 23, 12};
    const int Wd[4]  = {92, 46, 23, 12};
    const int S0_[4] = {0, 8464, 10580, 11109};

    if (t < 128) {
        int hh = t >> 4, lp = t & 15, l = lp >> 2;
        float ox = off_raw[(size_t)row * 256 + hh * 32 + lp * 2 + 0];
        float oy = off_raw[(size_t)row * 256 + hh * 32 + lp * 2 + 1];
        float rx = refp[((size_t)row * 4 + l) * 2 + 0];
        float ry = refp[((size_t)row * 4 + l) * 2 + 1];
        px_s[hh][lp] = rx * (float)Wd[l] + ox - 0.5f;
        py_s[hh][lp] = ry * (float)Hs[l] + oy - 0.5f;
    }
    if (t < 8) {
        int hh = t;
        float v[16];
        float m = -1e30f;
#pragma unroll
        for (int j = 0; j < 16; ++j) {
            v[j] = aw_raw[(size_t)row * 128 + hh * 16 + j];
            m = fmaxf(m, v[j]);
        }
        float ssum = 0.f;
#pragma unroll
        for (int j = 0; j < 16; ++j) { v[j] = __expf(v[j] - m); ssum += v[j]; }
        float inv = 1.f / ssum;
#pragma unroll
        for (int j = 0; j < 16; ++j) aw_s[hh][j] = v[j] * inv;
    }
    __syncthreads();

    const int h = t >> 5, d = t & 31;
    const ushort_t* vb = value + (size_t)b * 256 + h * 32 + d;
    float acc = 0.f;
#pragma unroll
    for (int l = 0; l < 4; ++l) {
        const int H = Hs[l], W = Wd[l], base = S0_[l];
#pragma unroll
        for (int p = 0; p < 4; ++p) {
            const int lp = l * 4 + p;
            float px = px_s[h][lp], py = py_s[h][lp];
            float x0f = floorf(px), y0f = floorf(py);
            int x0 = (int)x0f, y0 = (int)y0f;
            float wx = px - x0f, wy = py - y0f;
            float sv = 0.f;
#pragma unroll
            for (int dy = 0; dy < 2; ++dy) {
#pragma unroll
                for (int dx = 0; dx < 2; ++dx) {
                    int xi = x0 + dx, yi = y0 + dy;
                    float flag = (xi >= 0 && xi < W && yi >= 0 && yi < H) ? 1.f : 0.f;
                    int xc = xi < 0 ? 0 : (xi >= W ? W - 1 : xi);
                    int yc = yi < 0 ? 0 : (yi >= H ? H - 1 : yi);
                    float wgt = (dx ? wx : 1.f - wx) * (dy ? wy : 1.f - wy);
                    float gv = bf2f(vb[(size_t)(base + yc * W + xc) * 1024]);
                    sv = fmaf(wgt * flag, gv, sv);
                }
            }
            acc = fmaf(aw_s[h][lp], sv, acc);
        }
    }
    out[(size_t)row * 256 + h * 32 + d] = (ushort_t)f2bf1(acc);
}

// ---------------------------------------------------------------------------
extern "C" void kernel_launch(void* const* d_in, const int* in_sizes, int n_in,
                              void* d_out, int out_size, void* d_ws, size_t ws_size,
                              hipStream_t stream)
{
    const float* tgt    = (const float*)d_in[0];
    const float* qpos   = (const float*)d_in[1];
    const float* refp   = (const float*)d_in[2];
    const float* mem    = (const float*)d_in[3];
    const float* in_w   = (const float*)d_in[6];
    const float* in_b   = (const float*)d_in[7];
    const float* outp_w = (const float*)d_in[8];
    const float* outp_b = (const float*)d_in[9];
    const float* off_w  = (const float*)d_in[10];
    const float* off_b  = (const float*)d_in[11];
    const float* aw_w   = (const float*)d_in[12];
    const float* aw_b   = (const float*)d_in[13];
    const float* vp_w   = (const float*)d_in[14];
    const float* vp_b   = (const float*)d_in[15];
    const float* op_w   = (const float*)d_in[16];
    const float* op_b   = (const float*)d_in[17];
    const float* ln1g   = (const float*)d_in[18];
    const float* ln1b   = (const float*)d_in[19];
    const float* ln2g   = (const float*)d_in[20];
    const float* ln2b   = (const float*)d_in[21];
    const float* ln3g   = (const float*)d_in[22];
    const float* ln3b   = (const float*)d_in[23];
    const float* l1w    = (const float*)d_in[24];
    const float* l1b    = (const float*)d_in[25];
    const float* l2w    = (const float*)d_in[26];
    const float* l2b    = (const float*)d_in[27];
    float* out = (float*)d_out;
    float* ws  = (float*)d_ws;

    // workspace layout (float units)
    ushort_t* qkv16    = (ushort_t*)ws;                 // 691200 floats
    ushort_t* att16    = (ushort_t*)(ws + 691200);      // 230400
    float*    tmp      = ws + 921600;                   // 921600
    float*    tgt_a    = ws + 1843200;                  // 921600
    float*    off_raw  = ws + 2764800;                  // 921600
    float*    aw_raw   = ws + 3686400;                  // 460800
    ushort_t* att2_16  = (ushort_t*)(ws + 4147200);     // 230400
    float*    tgt_b    = ws + 4377600;                  // 921600
    ushort_t* value16  = (ushort_t*)(ws + 5299200);     // 5761536
    ushort_t* hidden16 = (ushort_t*)(ws + 11060736);    // 1843200

    dim3 b256(256);

    // 1. qkv + value projection (independent -> one dispatch)
    hipLaunchKernelGGL(proj_fused, dim3(1388), b256, 0, stream,
                       tgt, qpos, in_w, in_b, mem, vp_w, vp_b, qkv16, value16);
    // 2. flash self-attention
    hipLaunchKernelGGL(sa_flash16, dim3(15, 32), b256, 0, stream, qkv16, att16);
    // 3. out-proj -> tmp (fp32)
    hipLaunchKernelGGL(gemm16_f32, dim3(57, 4), b256, 0, stream,
                       att16, outp_w, outp_b, tmp, NROW, 256, 256, 256);
    // 4. LN2-fused offset/aw GEMMs; by==0 writes tgt_a
    hipLaunchKernelGGL(offaw_ln, dim3(57, 6), b256, 0, stream,
                       tgt, tmp, qpos, ln2g, ln2b,
                       off_w, off_b, aw_w, aw_b, off_raw, aw_raw, tgt_a);
    // 5. deformable sampling (bf16 out)
    hipLaunchKernelGGL(msdeform16, dim3(3600), b256, 0, stream,
                       off_raw, aw_raw, refp, value16, att2_16);
    // 6. oproj -> tmp
    hipLaunchKernelGGL(gemm16_f32, dim3(57, 4), b256, 0, stream,
                       att2_16, op_w, op_b, tmp, NROW, 256, 256, 256);
    // 7. LN1-fused FFN1 (+ReLU, bf16 out); by==0 writes tgt_b
    hipLaunchKernelGGL(ffn1_ln, dim3(57, 16), b256, 0, stream,
                       tgt_a, tmp, ln1g, ln1b, l1w, l1b, hidden16, tgt_b);
    // 8. FFN2 -> tmp
    hipLaunchKernelGGL(gemm16_f32, dim3(57, 4), b256, 0, stream,
                       hidden16, l2w, l2b, tmp, NROW, 256, 1024, 256);
    // 9. LN3 -> d_out
    hipLaunchKernelGGL(ln_resid16, dim3(3600), b256, 0, stream,
                       tgt_b, tmp, ln3g, ln3b, out);
}

// Round 9
// 292.334 us; speedup vs baseline: 1.3886x; 1.3886x over previous
//
#include <hip/hip_runtime.h>
#include <math.h>

#define D_MODEL 256
#define NHEAD   8
#define NLVL    4
#define NPTS    4
#define DHEAD   32
#define DFFN    1024
#define NQ      900
#define BSZ     4
#define NROW    (NQ * BSZ)      // 3600
#define S_TOT   11253
#define VROWS   (S_TOT * BSZ)   // 45012
#define SASCALE 0.17677669529663687f

typedef __attribute__((ext_vector_type(8))) short short8;
typedef __attribute__((ext_vector_type(4))) float f32x4;
typedef unsigned short ushort_t;

static __device__ __forceinline__ unsigned f2bf1(float f) {
    unsigned u = __float_as_uint(f);
    return (u + 0x7FFFu + ((u >> 16) & 1u)) >> 16;
}
static __device__ __forceinline__ unsigned pack2bf(float x, float y) {
    return f2bf1(x) | (f2bf1(y) << 16);
}
static __device__ __forceinline__ float bf2f(ushort_t u) {
    return __uint_as_float(((unsigned)u) << 16);
}

#define GPAD 72

// ---------------------------------------------------------------------------
// proj_fused: qkv projection (blocks 0..683) + value projection (684..1387).
// Independent workloads merged into one dispatch (proven R8-safe merge).
// ---------------------------------------------------------------------------
__global__ __launch_bounds__(256) void proj_fused(
    const float* __restrict__ tgt, const float* __restrict__ qpos,
    const float* __restrict__ in_w, const float* __restrict__ in_b,
    const float* __restrict__ mem, const float* __restrict__ vp_w,
    const float* __restrict__ vp_b,
    ushort_t* __restrict__ qkv16, ushort_t* __restrict__ value16)
{
    __shared__ ushort_t As[64 * GPAD];
    __shared__ ushort_t Ws[256 * GPAD];

    const int t    = threadIdx.x;
    const int bid  = blockIdx.x;
    const int trow = t >> 2;
    const int tk   = (t & 3) << 4;
    const int wv   = t >> 6;
    const int ln   = t & 63;
    const int L    = ln & 15;
    const int quad = ln >> 4;

    if (bid < 684) {
        // ---------------- QKV path ----------------
        const int m0 = (bid % 57) * 64;
        const int n0 = (bid / 57) * 64;
        const bool addpos = (n0 < 512);
        const float oscale = (n0 < 256) ? SASCALE : 1.f;

        f32x4 acc[4] = {{0.f,0.f,0.f,0.f},{0.f,0.f,0.f,0.f},
                        {0.f,0.f,0.f,0.f},{0.f,0.f,0.f,0.f}};

        for (int k0 = 0; k0 < 256; k0 += 64) {
            {
                int m = m0 + trow;
                float4 a0, a1, a2, a3;
                if (m < NROW) {
                    const float* ap = tgt + (size_t)m * 256 + k0 + tk;
                    a0 = *(const float4*)(ap + 0);
                    a1 = *(const float4*)(ap + 4);
                    a2 = *(const float4*)(ap + 8);
                    a3 = *(const float4*)(ap + 12);
                    if (addpos) {
                        const float* pp = qpos + (size_t)m * 256 + k0 + tk;
                        float4 p0 = *(const float4*)(pp + 0);
                        float4 p1 = *(const float4*)(pp + 4);
                        float4 p2 = *(const float4*)(pp + 8);
                        float4 p3 = *(const float4*)(pp + 12);
                        a0.x += p0.x; a0.y += p0.y; a0.z += p0.z; a0.w += p0.w;
                        a1.x += p1.x; a1.y += p1.y; a1.z += p1.z; a1.w += p1.w;
                        a2.x += p2.x; a2.y += p2.y; a2.z += p2.z; a2.w += p2.w;
                        a3.x += p3.x; a3.y += p3.y; a3.z += p3.z; a3.w += p3.w;
                    }
                } else {
                    a0 = a1 = a2 = a3 = make_float4(0.f, 0.f, 0.f, 0.f);
                }
                uint4 u0, u1;
                u0.x = pack2bf(a0.x, a0.y); u0.y = pack2bf(a0.z, a0.w);
                u0.z = pack2bf(a1.x, a1.y); u0.w = pack2bf(a1.z, a1.w);
                u1.x = pack2bf(a2.x, a2.y); u1.y = pack2bf(a2.z, a2.w);
                u1.z = pack2bf(a3.x, a3.y); u1.w = pack2bf(a3.z, a3.w);
                *(uint4*)&As[trow * GPAD + tk + 0] = u0;
                *(uint4*)&As[trow * GPAD + tk + 8] = u1;
            }
            {
                int n = n0 + trow;
                const float* wp = in_w + (size_t)n * 256 + k0 + tk;
                float4 a0 = *(const float4*)(wp + 0);
                float4 a1 = *(const float4*)(wp + 4);
                float4 a2 = *(const float4*)(wp + 8);
                float4 a3 = *(const float4*)(wp + 12);
                uint4 u0, u1;
                u0.x = pack2bf(a0.x, a0.y); u0.y = pack2bf(a0.z, a0.w);
                u0.z = pack2bf(a1.x, a1.y); u0.w = pack2bf(a1.z, a1.w);
                u1.x = pack2bf(a2.x, a2.y); u1.y = pack2bf(a2.z, a2.w);
                u1.z = pack2bf(a3.x, a3.y); u1.w = pack2bf(a3.z, a3.w);
                *(uint4*)&Ws[trow * GPAD + tk + 0] = u0;
                *(uint4*)&Ws[trow * GPAD + tk + 8] = u1;
            }
            __syncthreads();
#pragma unroll
            for (int kh = 0; kh < 2; ++kh) {
                short8 af = *(const short8*)&As[(wv * 16 + L) * GPAD + kh * 32 + quad * 8];
#pragma unroll
                for (int cb = 0; cb < 4; ++cb) {
                    short8 bf = *(const short8*)&Ws[(cb * 16 + L) * GPAD + kh * 32 + quad * 8];
                    acc[cb] = __builtin_amdgcn_mfma_f32_16x16x32_bf16(af, bf, acc[cb], 0, 0, 0);
                }
            }
            __syncthreads();
        }
#pragma unroll
        for (int cb = 0; cb < 4; ++cb) {
            int col = n0 + cb * 16 + L;
            float bv = in_b[col];
#pragma unroll
            for (int i = 0; i < 4; ++i) {
                int m = m0 + wv * 16 + quad * 4 + i;
                if (m < NROW)
                    qkv16[(size_t)m * 768 + col] = (ushort_t)f2bf1((acc[cb][i] + bv) * oscale);
            }
        }
    } else {
        // ---------------- value-projection path ----------------
        const int m0 = (bid - 684) * 64;

        f32x4 acc[16];
#pragma unroll
        for (int i = 0; i < 16; ++i) acc[i] = (f32x4){0.f, 0.f, 0.f, 0.f};

        for (int k0 = 0; k0 < 256; k0 += 64) {
            {
                int m = m0 + trow;
                float4 a0, a1, a2, a3;
                if (m < VROWS) {
                    const float* ap = mem + (size_t)m * 256 + k0 + tk;
                    a0 = *(const float4*)(ap + 0);
                    a1 = *(const float4*)(ap + 4);
                    a2 = *(const float4*)(ap + 8);
                    a3 = *(const float4*)(ap + 12);
                } else {
                    a0 = a1 = a2 = a3 = make_float4(0.f, 0.f, 0.f, 0.f);
                }
                uint4 u0, u1;
                u0.x = pack2bf(a0.x, a0.y); u0.y = pack2bf(a0.z, a0.w);
                u0.z = pack2bf(a1.x, a1.y); u0.w = pack2bf(a1.z, a1.w);
                u1.x = pack2bf(a2.x, a2.y); u1.y = pack2bf(a2.z, a2.w);
                u1.z = pack2bf(a3.x, a3.y); u1.w = pack2bf(a3.z, a3.w);
                *(uint4*)&As[trow * GPAD + tk + 0] = u0;
                *(uint4*)&As[trow * GPAD + tk + 8] = u1;
            }
#pragma unroll
            for (int wb = 0; wb < 4; ++wb) {
                int n = wb * 64 + trow;
                const float* wp = vp_w + (size_t)n * 256 + k0 + tk;
                float4 a0 = *(const float4*)(wp + 0);
                float4 a1 = *(const float4*)(wp + 4);
                float4 a2 = *(const float4*)(wp + 8);
                float4 a3 = *(const float4*)(wp + 12);
                uint4 u0, u1;
                u0.x = pack2bf(a0.x, a0.y); u0.y = pack2bf(a0.z, a0.w);
                u0.z = pack2bf(a1.x, a1.y); u0.w = pack2bf(a1.z, a1.w);
                u1.x = pack2bf(a2.x, a2.y); u1.y = pack2bf(a2.z, a2.w);
                u1.z = pack2bf(a3.x, a3.y); u1.w = pack2bf(a3.z, a3.w);
                *(uint4*)&Ws[n * GPAD + tk + 0] = u0;
                *(uint4*)&Ws[n * GPAD + tk + 8] = u1;
            }
            __syncthreads();
#pragma unroll
            for (int kh = 0; kh < 2; ++kh) {
                short8 af = *(const short8*)&As[(wv * 16 + L) * GPAD + kh * 32 + quad * 8];
#pragma unroll
                for (int cb = 0; cb < 16; ++cb) {
                    short8 bf = *(const short8*)&Ws[(cb * 16 + L) * GPAD + kh * 32 + quad * 8];
                    acc[cb] = __builtin_amdgcn_mfma_f32_16x16x32_bf16(af, bf, acc[cb], 0, 0, 0);
                }
            }
            __syncthreads();
        }

        ushort_t* Cs = Ws;
#pragma unroll
        for (int cb = 0; cb < 16; ++cb) {
            int col = cb * 16 + L;
            float bv = vp_b[col];
#pragma unroll
            for (int i = 0; i < 4; ++i) {
                int r = wv * 16 + quad * 4 + i;
                Cs[r * 264 + col] = (ushort_t)f2bf1(acc[cb][i] + bv);
            }
        }
        __syncthreads();
        {
            int r  = t >> 2;
            int ch = (t & 3) * 64;
            int m  = m0 + r;
            if (m < VROWS) {
                const ushort_t* src = &Cs[r * 264 + ch];
                uint4* dst = (uint4*)(value16 + (size_t)m * 256 + ch);
#pragma unroll
                for (int j = 0; j < 8; ++j)
                    dst[j] = *(const uint4*)(src + j * 8);
            }
        }
    }
}

// ---------------------------------------------------------------------------
// MFMA flash self-attention, bf16 in / bf16 out (unchanged).
// ---------------------------------------------------------------------------
__global__ __launch_bounds__(256) void sa_flash16(
    const ushort_t* __restrict__ qkv, ushort_t* __restrict__ attn_out)
{
    __shared__ ushort_t Ks[2 * 2080];
    __shared__ ushort_t Vt[2 * 2304];
    __shared__ ushort_t Ps[4 * 1152];

    const int t    = threadIdx.x;
    const int q0   = blockIdx.x * 64;
    const int b    = blockIdx.y & 3;
    const int h    = blockIdx.y >> 2;
    const int wv   = t >> 6;
    const int ln   = t & 63;
    const int L    = ln & 15;
    const int quad = ln >> 4;

    union { uint4 u; short8 s; } qu;
    qu.u = make_uint4(0u, 0u, 0u, 0u);
    {
        int q = q0 + wv * 16 + L;
        if (q < NQ)
            qu.u = *(const uint4*)(qkv + ((size_t)q * 4 + b) * 768 + h * 32 + quad * 8);
    }
    const short8 qf = qu.s;

    float mrun = -1e30f, lrun = 0.f;
    f32x4 oacc[2] = {{0.f,0.f,0.f,0.f},{0.f,0.f,0.f,0.f}};

    const int skey = t >> 2;
    const int sdg  = t & 3;

    int it = 0;
    for (int k0 = 0; k0 < NQ; k0 += 64, it ^= 1) {
        {
            int kg = k0 + skey;
            uint4 ku = make_uint4(0u,0u,0u,0u), vu = make_uint4(0u,0u,0u,0u);
            if (kg < NQ) {
                const ushort_t* base = qkv + ((size_t)kg * 4 + b) * 768 + 256 + h * 32 + sdg * 8;
                ku = *(const uint4*)base;
                vu = *(const uint4*)(base + 256);
            }
            *(uint4*)&Ks[it * 2080 + sdg * 520 + skey * 8] = ku;
            ushort_t* vp = &Vt[it * 2304 + sdg * 8 * 72 + skey];
            vp[0 * 72] = (ushort_t)(vu.x & 0xffffu);
            vp[1 * 72] = (ushort_t)(vu.x >> 16);
            vp[2 * 72] = (ushort_t)(vu.y & 0xffffu);
            vp[3 * 72] = (ushort_t)(vu.y >> 16);
            vp[4 * 72] = (ushort_t)(vu.z & 0xffffu);
            vp[5 * 72] = (ushort_t)(vu.z >> 16);
            vp[6 * 72] = (ushort_t)(vu.w & 0xffffu);
            vp[7 * 72] = (ushort_t)(vu.w >> 16);
        }
        __syncthreads();

        f32x4 sacc[4] = {{0.f,0.f,0.f,0.f},{0.f,0.f,0.f,0.f},
                         {0.f,0.f,0.f,0.f},{0.f,0.f,0.f,0.f}};
#pragma unroll
        for (int cb = 0; cb < 4; ++cb) {
            short8 kf = *(const short8*)&Ks[it * 2080 + quad * 520 + (cb * 16 + L) * 8];
            sacc[cb] = __builtin_amdgcn_mfma_f32_16x16x32_bf16(kf, qf, sacc[cb], 0, 0, 0);
        }
        if (k0 + 64 > NQ) {
#pragma unroll
            for (int cb = 0; cb < 4; ++cb)
#pragma unroll
                for (int i = 0; i < 4; ++i)
                    if (k0 + cb * 16 + quad * 4 + i >= NQ) sacc[cb][i] = -1e30f;
        }

        float ml = -1e30f;
#pragma unroll
        for (int cb = 0; cb < 4; ++cb)
#pragma unroll
            for (int i = 0; i < 4; ++i) ml = fmaxf(ml, sacc[cb][i]);
        ml = fmaxf(ml, __shfl_xor(ml, 16, 64));
        ml = fmaxf(ml, __shfl_xor(ml, 32, 64));
        float mnew  = fmaxf(mrun, ml);
        float alpha = __expf(mrun - mnew);
        float p[16];
        float rs = 0.f;
#pragma unroll
        for (int cb = 0; cb < 4; ++cb)
#pragma unroll
            for (int i = 0; i < 4; ++i) {
                float e = __expf(sacc[cb][i] - mnew);
                p[cb * 4 + i] = e;
                rs += e;
            }
        rs += __shfl_xor(rs, 16, 64);
        rs += __shfl_xor(rs, 32, 64);
        lrun = lrun * alpha + rs;
        mrun = mnew;

        {
            ushort_t* pw = &Ps[wv * 1152 + L * 72];
#pragma unroll
            for (int cb = 0; cb < 4; ++cb) {
                uint2 u;
                u.x = pack2bf(p[cb * 4 + 0], p[cb * 4 + 1]);
                u.y = pack2bf(p[cb * 4 + 2], p[cb * 4 + 3]);
                *(uint2*)&pw[cb * 16 + quad * 4] = u;
            }
        }
#pragma unroll
        for (int i = 0; i < 4; ++i) {
            float ai = __shfl(alpha, quad * 4 + i, 64);
            oacc[0][i] *= ai;
            oacc[1][i] *= ai;
        }
        __syncthreads();

#pragma unroll
        for (int ks = 0; ks < 2; ++ks) {
            short8 pf = *(const short8*)&Ps[wv * 1152 + L * 72 + ks * 32 + quad * 8];
#pragma unroll
            for (int db = 0; db < 2; ++db) {
                short8 vf = *(const short8*)&Vt[it * 2304 + (db * 16 + L) * 72 + ks * 32 + quad * 8];
                oacc[db] = __builtin_amdgcn_mfma_f32_16x16x32_bf16(pf, vf, oacc[db], 0, 0, 0);
            }
        }
    }

#pragma unroll
    for (int i = 0; i < 4; ++i) {
        float lq = __shfl(lrun, quad * 4 + i, 64);
        float li = 1.f / lq;
        int q = q0 + wv * 16 + quad * 4 + i;
        if (q < NQ) {
            ushort_t* op = attn_out + ((size_t)q * 4 + b) * 256 + h * 32 + L;
            op[0]  = (ushort_t)f2bf1(oacc[0][i] * li);
            op[16] = (ushort_t)f2bf1(oacc[1][i] * li);
        }
    }
}

// ---------------------------------------------------------------------------
// Plain 64x64-tile GEMM, bf16 A, fp32 W, fp32 C (proven-fast).
// ---------------------------------------------------------------------------
__global__ __launch_bounds__(256) void gemm16_f32(
    const ushort_t* __restrict__ A, const float* __restrict__ W,
    const float* __restrict__ bias, float* __restrict__ C,
    int M, int N, int K, int ldc)
{
    __shared__ ushort_t As[64 * GPAD];
    __shared__ ushort_t Ws[64 * GPAD];

    const int t  = threadIdx.x;
    const int m0 = blockIdx.x * 64;
    const int n0 = blockIdx.y * 64;
    const int trow = t >> 2;
    const int tk   = (t & 3) << 4;
    const int wv   = t >> 6;
    const int ln   = t & 63;
    const int L    = ln & 15;
    const int quad = ln >> 4;

    f32x4 acc[4] = {{0.f,0.f,0.f,0.f},{0.f,0.f,0.f,0.f},
                    {0.f,0.f,0.f,0.f},{0.f,0.f,0.f,0.f}};

    for (int k0 = 0; k0 < K; k0 += 64) {
        {
            int m = m0 + trow;
            uint4 a0 = make_uint4(0u,0u,0u,0u), a1 = make_uint4(0u,0u,0u,0u);
            if (m < M) {
                const ushort_t* ap = A + (size_t)m * K + k0 + tk;
                a0 = *(const uint4*)ap;
                a1 = *(const uint4*)(ap + 8);
            }
            *(uint4*)&As[trow * GPAD + tk + 0] = a0;
            *(uint4*)&As[trow * GPAD + tk + 8] = a1;
        }
        {
            int n = n0 + trow;
            const float* wp = W + (size_t)n * K + k0 + tk;
            float4 a0 = *(const float4*)(wp + 0);
            float4 a1 = *(const float4*)(wp + 4);
            float4 a2 = *(const float4*)(wp + 8);
            float4 a3 = *(const float4*)(wp + 12);
            uint4 u0, u1;
            u0.x = pack2bf(a0.x, a0.y); u0.y = pack2bf(a0.z, a0.w);
            u0.z = pack2bf(a1.x, a1.y); u0.w = pack2bf(a1.z, a1.w);
            u1.x = pack2bf(a2.x, a2.y); u1.y = pack2bf(a2.z, a2.w);
            u1.z = pack2bf(a3.x, a3.y); u1.w = pack2bf(a3.z, a3.w);
            *(uint4*)&Ws[trow * GPAD + tk + 0] = u0;
            *(uint4*)&Ws[trow * GPAD + tk + 8] = u1;
        }
        __syncthreads();
#pragma unroll
        for (int kh = 0; kh < 2; ++kh) {
            short8 af = *(const short8*)&As[(wv * 16 + L) * GPAD + kh * 32 + quad * 8];
#pragma unroll
            for (int cb = 0; cb < 4; ++cb) {
                short8 bf = *(const short8*)&Ws[(cb * 16 + L) * GPAD + kh * 32 + quad * 8];
                acc[cb] = __builtin_amdgcn_mfma_f32_16x16x32_bf16(af, bf, acc[cb], 0, 0, 0);
            }
        }
        __syncthreads();
    }
#pragma unroll
    for (int cb = 0; cb < 4; ++cb) {
        int col = n0 + cb * 16 + L;
        float bv = bias[col];
#pragma unroll
        for (int i = 0; i < 4; ++i) {
            int m = m0 + wv * 16 + quad * 4 + i;
            if (m < M)
                C[(size_t)m * ldc + col] = acc[cb][i] + bv;
        }
    }
}

// ---------------------------------------------------------------------------
// Residual + LayerNorm + optional bf16 out2(+pos). One block per row.
// ---------------------------------------------------------------------------
__global__ __launch_bounds__(256) void ln_resid16(
    const float* __restrict__ xa, const float* __restrict__ xb,
    const float* __restrict__ gam, const float* __restrict__ bet,
    float* __restrict__ out, const float* __restrict__ pos,
    ushort_t* __restrict__ out2)
{
    const int row = blockIdx.x;
    const int t = threadIdx.x;
    float x = xa[(size_t)row * D_MODEL + t] + xb[(size_t)row * D_MODEL + t];
    float s = x, s2 = x * x;
#pragma unroll
    for (int off = 32; off > 0; off >>= 1) {
        s  += __shfl_down(s, off, 64);
        s2 += __shfl_down(s2, off, 64);
    }
    __shared__ float rs[4], rs2[4];
    __shared__ float mean_s, rstd_s;
    int wid = t >> 6, lane = t & 63;
    if (lane == 0) { rs[wid] = s; rs2[wid] = s2; }
    __syncthreads();
    if (t == 0) {
        float S = rs[0] + rs[1] + rs[2] + rs[3];
        float S2 = rs2[0] + rs2[1] + rs2[2] + rs2[3];
        float mean = S * (1.f / 256.f);
        float var = S2 * (1.f / 256.f) - mean * mean;
        mean_s = mean;
        rstd_s = rsqrtf(var + 1e-5f);
    }
    __syncthreads();
    float y = (x - mean_s) * rstd_s * gam[t] + bet[t];
    out[(size_t)row * D_MODEL + t] = y;
    if (out2) {
        float o2 = y + (pos ? pos[(size_t)row * D_MODEL + t] : 0.f);
        out2[(size_t)row * D_MODEL + t] = (ushort_t)f2bf1(o2);
    }
}

// ---------------------------------------------------------------------------
// Fused offset + attention-weight GEMM (proven R7 shape).
// ---------------------------------------------------------------------------
__global__ __launch_bounds__(256) void offaw16(
    const ushort_t* __restrict__ A,
    const float* __restrict__ off_w, const float* __restrict__ off_b,
    const float* __restrict__ aw_w, const float* __restrict__ aw_b,
    float* __restrict__ off_raw, float* __restrict__ aw_raw)
{
    __shared__ ushort_t As[64 * GPAD];
    __shared__ ushort_t Ws[64 * GPAD];

    const int t  = threadIdx.x;
    const int m0 = blockIdx.x * 64;
    const int by = blockIdx.y;
    const bool isaw = (by >= 4);
    const int n0 = isaw ? (by - 4) * 64 : by * 64;
    const float* W  = isaw ? aw_w : off_w;
    const float* bs = isaw ? aw_b : off_b;
    float* C = isaw ? aw_raw : off_raw;
    const int ldc = isaw ? 128 : 256;

    const int trow = t >> 2;
    const int tk   = (t & 3) << 4;
    const int wv   = t >> 6;
    const int ln   = t & 63;
    const int L    = ln & 15;
    const int quad = ln >> 4;

    f32x4 acc[4] = {{0.f,0.f,0.f,0.f},{0.f,0.f,0.f,0.f},
                    {0.f,0.f,0.f,0.f},{0.f,0.f,0.f,0.f}};

    for (int k0 = 0; k0 < 256; k0 += 64) {
        {
            int m = m0 + trow;
            uint4 a0 = make_uint4(0u,0u,0u,0u), a1 = make_uint4(0u,0u,0u,0u);
            if (m < NROW) {
                const ushort_t* ap = A + (size_t)m * 256 + k0 + tk;
                a0 = *(const uint4*)ap;
                a1 = *(const uint4*)(ap + 8);
            }
            *(uint4*)&As[trow * GPAD + tk + 0] = a0;
            *(uint4*)&As[trow * GPAD + tk + 8] = a1;
        }
        {
            int n = n0 + trow;
            const float* wp = W + (size_t)n * 256 + k0 + tk;
            float4 a0 = *(const float4*)(wp + 0);
            float4 a1 = *(const float4*)(wp + 4);
            float4 a2 = *(const float4*)(wp + 8);
            float4 a3 = *(const float4*)(wp + 12);
            uint4 u0, u1;
            u0.x = pack2bf(a0.x, a0.y); u0.y = pack2bf(a0.z, a0.w);
            u0.z = pack2bf(a1.x, a1.y); u0.w = pack2bf(a1.z, a1.w);
            u1.x = pack2bf(a2.x, a2.y); u1.y = pack2bf(a2.z, a2.w);
            u1.z = pack2bf(a3.x, a3.y); u1.w = pack2bf(a3.z, a3.w);
            *(uint4*)&Ws[trow * GPAD + tk + 0] = u0;
            *(uint4*)&Ws[trow * GPAD + tk + 8] = u1;
        }
        __syncthreads();
#pragma unroll
        for (int kh = 0; kh < 2; ++kh) {
            short8 af = *(const short8*)&As[(wv * 16 + L) * GPAD + kh * 32 + quad * 8];
#pragma unroll
            for (int cb = 0; cb < 4; ++cb) {
                short8 bf = *(const short8*)&Ws[(cb * 16 + L) * GPAD + kh * 32 + quad * 8];
                acc[cb] = __builtin_amdgcn_mfma_f32_16x16x32_bf16(af, bf, acc[cb], 0, 0, 0);
            }
        }
        __syncthreads();
    }
#pragma unroll
    for (int cb = 0; cb < 4; ++cb) {
        int col = n0 + cb * 16 + L;
        float bv = bs[col];
#pragma unroll
        for (int i = 0; i < 4; ++i) {
            int m = m0 + wv * 16 + quad * 4 + i;
            if (m < NROW)
                C[(size_t)m * ldc + col] = acc[cb][i] + bv;
        }
    }
}

// ---------------------------------------------------------------------------
// Generic A-bf16 -> C-bf16 GEMM (FFN1 with ReLU).
// ---------------------------------------------------------------------------
__global__ __launch_bounds__(256) void gemm16_16(
    const ushort_t* __restrict__ A, const float* __restrict__ W,
    const float* __restrict__ bias, ushort_t* __restrict__ C,
    int M, int N, int K, int ldc, int relu)
{
    __shared__ ushort_t As[64 * GPAD];
    __shared__ ushort_t Ws[64 * GPAD];

    const int t  = threadIdx.x;
    const int m0 = blockIdx.x * 64;
    const int n0 = blockIdx.y * 64;
    const int trow = t >> 2;
    const int tk   = (t & 3) << 4;
    const int wv   = t >> 6;
    const int ln   = t & 63;
    const int L    = ln & 15;
    const int quad = ln >> 4;

    f32x4 acc[4] = {{0.f,0.f,0.f,0.f},{0.f,0.f,0.f,0.f},
                    {0.f,0.f,0.f,0.f},{0.f,0.f,0.f,0.f}};

    for (int k0 = 0; k0 < K; k0 += 64) {
        {
            int m = m0 + trow;
            uint4 a0 = make_uint4(0u,0u,0u,0u), a1 = make_uint4(0u,0u,0u,0u);
            if (m < M) {
                const ushort_t* ap = A + (size_t)m * K + k0 + tk;
                a0 = *(const uint4*)ap;
                a1 = *(const uint4*)(ap + 8);
            }
            *(uint4*)&As[trow * GPAD + tk + 0] = a0;
            *(uint4*)&As[trow * GPAD + tk + 8] = a1;
        }
        {
            int n = n0 + trow;
            const float* wp = W + (size_t)n * K + k0 + tk;
            float4 a0 = *(const float4*)(wp + 0);
            float4 a1 = *(const float4*)(wp + 4);
            float4 a2 = *(const float4*)(wp + 8);
            float4 a3 = *(const float4*)(wp + 12);
            uint4 u0, u1;
            u0.x = pack2bf(a0.x, a0.y); u0.y = pack2bf(a0.z, a0.w);
            u0.z = pack2bf(a1.x, a1.y); u0.w = pack2bf(a1.z, a1.w);
            u1.x = pack2bf(a2.x, a2.y); u1.y = pack2bf(a2.z, a2.w);
            u1.z = pack2bf(a3.x, a3.y); u1.w = pack2bf(a3.z, a3.w);
            *(uint4*)&Ws[trow * GPAD + tk + 0] = u0;
            *(uint4*)&Ws[trow * GPAD + tk + 8] = u1;
        }
        __syncthreads();
#pragma unroll
        for (int kh = 0; kh < 2; ++kh) {
            short8 af = *(const short8*)&As[(wv * 16 + L) * GPAD + kh * 32 + quad * 8];
#pragma unroll
            for (int cb = 0; cb < 4; ++cb) {
                short8 bf = *(const short8*)&Ws[(cb * 16 + L) * GPAD + kh * 32 + quad * 8];
                acc[cb] = __builtin_amdgcn_mfma_f32_16x16x32_bf16(af, bf, acc[cb], 0, 0, 0);
            }
        }
        __syncthreads();
    }
#pragma unroll
    for (int cb = 0; cb < 4; ++cb) {
        int col = n0 + cb * 16 + L;
        float bv = bias[col];
#pragma unroll
        for (int i = 0; i < 4; ++i) {
            int m = m0 + wv * 16 + quad * 4 + i;
            if (m < M) {
                float o = acc[cb][i] + bv;
                if (relu) o = fmaxf(o, 0.f);
                C[(size_t)m * ldc + col] = (ushort_t)f2bf1(o);
            }
        }
    }
}

// ---------------------------------------------------------------------------
// Multi-scale deformable sampling (unchanged).
// ---------------------------------------------------------------------------
__global__ __launch_bounds__(256) void msdeform16(
    const float* __restrict__ off_raw, const float* __restrict__ aw_raw,
    const float* __restrict__ refp, const ushort_t* __restrict__ value,
    ushort_t* __restrict__ out)
{
    const int row = blockIdx.x;   // q*4+b
    const int b = row & 3;
    const int t = threadIdx.x;

    __shared__ float aw_s[8][17];
    __shared__ float px_s[8][16];
    __shared__ float py_s[8][16];

    const int Hs[4]  = {92, 46, 23, 12};
    const int Wd[4]  = {92, 46, 23, 12};
    const int S0_[4] = {0, 8464, 10580, 11109};

    if (t < 128) {
        int hh = t >> 4, lp = t & 15, l = lp >> 2;
        float ox = off_raw[(size_t)row * 256 + hh * 32 + lp * 2 + 0];
        float oy = off_raw[(size_t)row * 256 + hh * 32 + lp * 2 + 1];
        float rx = refp[((size_t)row * 4 + l) * 2 + 0];
        float ry = refp[((size_t)row * 4 + l) * 2 + 1];
        px_s[hh][lp] = rx * (float)Wd[l] + ox - 0.5f;
        py_s[hh][lp] = ry * (float)Hs[l] + oy - 0.5f;
    }
    if (t < 8) {
        int hh = t;
        float v[16];
        float m = -1e30f;
#pragma unroll
        for (int j = 0; j < 16; ++j) {
            v[j] = aw_raw[(size_t)row * 128 + hh * 16 + j];
            m = fmaxf(m, v[j]);
        }
        float ssum = 0.f;
#pragma unroll
        for (int j = 0; j < 16; ++j) { v[j] = __expf(v[j] - m); ssum += v[j]; }
        float inv = 1.f / ssum;
#pragma unroll
        for (int j = 0; j < 16; ++j) aw_s[hh][j] = v[j] * inv;
    }
    __syncthreads();

    const int h = t >> 5, d = t & 31;
    const ushort_t* vb = value + (size_t)b * 256 + h * 32 + d;
    float acc = 0.f;
#pragma unroll
    for (int l = 0; l < 4; ++l) {
        const int H = Hs[l], W = Wd[l], base = S0_[l];
#pragma unroll
        for (int p = 0; p < 4; ++p) {
            const int lp = l * 4 + p;
            float px = px_s[h][lp], py = py_s[h][lp];
            float x0f = floorf(px), y0f = floorf(py);
            int x0 = (int)x0f, y0 = (int)y0f;
            float wx = px - x0f, wy = py - y0f;
            float sv = 0.f;
#pragma unroll
            for (int dy = 0; dy < 2; ++dy) {
#pragma unroll
                for (int dx = 0; dx < 2; ++dx) {
                    int xi = x0 + dx, yi = y0 + dy;
                    float flag = (xi >= 0 && xi < W && yi >= 0 && yi < H) ? 1.f : 0.f;
                    int xc = xi < 0 ? 0 : (xi >= W ? W - 1 : xi);
                    int yc = yi < 0 ? 0 : (yi >= H ? H - 1 : yi);
                    float wgt = (dx ? wx : 1.f - wx) * (dy ? wy : 1.f - wy);
                    float gv = bf2f(vb[(size_t)(base + yc * W + xc) * 1024]);
                    sv = fmaf(wgt * flag, gv, sv);
                }
            }
            acc = fmaf(aw_s[h][lp], sv, acc);
        }
    }
    out[(size_t)row * 256 + h * 32 + d] = (ushort_t)f2bf1(acc);
}

// ---------------------------------------------------------------------------
extern "C" void kernel_launch(void* const* d_in, const int* in_sizes, int n_in,
                              void* d_out, int out_size, void* d_ws, size_t ws_size,
                              hipStream_t stream)
{
    const float* tgt    = (const float*)d_in[0];
    const float* qpos   = (const float*)d_in[1];
    const float* refp   = (const float*)d_in[2];
    const float* mem    = (const float*)d_in[3];
    const float* in_w   = (const float*)d_in[6];
    const float* in_b   = (const float*)d_in[7];
    const float* outp_w = (const float*)d_in[8];
    const float* outp_b = (const float*)d_in[9];
    const float* off_w  = (const float*)d_in[10];
    const float* off_b  = (const float*)d_in[11];
    const float* aw_w   = (const float*)d_in[12];
    const float* aw_b   = (const float*)d_in[13];
    const float* vp_w   = (const float*)d_in[14];
    const float* vp_b   = (const float*)d_in[15];
    const float* op_w   = (const float*)d_in[16];
    const float* op_b   = (const float*)d_in[17];
    const float* ln1g   = (const float*)d_in[18];
    const float* ln1b   = (const float*)d_in[19];
    const float* ln2g   = (const float*)d_in[20];
    const float* ln2b   = (const float*)d_in[21];
    const float* ln3g   = (const float*)d_in[22];
    const float* ln3b   = (const float*)d_in[23];
    const float* l1w    = (const float*)d_in[24];
    const float* l1b    = (const float*)d_in[25];
    const float* l2w    = (const float*)d_in[26];
    const float* l2b    = (const float*)d_in[27];
    float* out = (float*)d_out;
    float* ws  = (float*)d_ws;

    // workspace layout (float units)
    ushort_t* qkv16    = (ushort_t*)ws;                 // 691200 floats
    ushort_t* att16    = (ushort_t*)(ws + 691200);      // 230400
    float*    tmp      = ws + 921600;                   // 921600
    float*    tgt_a    = ws + 1843200;                  // 921600
    ushort_t* xca16    = (ushort_t*)(ws + 2764800);     // 230400
    float*    off_raw  = ws + 2995200;                  // 921600
    float*    aw_raw   = ws + 3916800;                  // 460800
    ushort_t* att2_16  = (ushort_t*)(ws + 4377600);     // 230400
    float*    tgt_b    = ws + 4608000;                  // 921600
    ushort_t* tgtb16   = (ushort_t*)(ws + 5529600);     // 230400
    ushort_t* value16  = (ushort_t*)(ws + 5760000);     // 5761536
    ushort_t* hidden16 = (ushort_t*)(ws + 11521536);    // 1843200

    dim3 b256(256);

    // 1. qkv + value projection (independent -> one dispatch)
    hipLaunchKernelGGL(proj_fused, dim3(1388), b256, 0, stream,
                       tgt, qpos, in_w, in_b, mem, vp_w, vp_b, qkv16, value16);
    // 2. flash self-attention
    hipLaunchKernelGGL(sa_flash16, dim3(15, 32), b256, 0, stream, qkv16, att16);
    // 3. out-proj -> tmp (fp32)
    hipLaunchKernelGGL(gemm16_f32, dim3(57, 4), b256, 0, stream,
                       att16, outp_w, outp_b, tmp, NROW, 256, 256, 256);
    // 4. LN2: tgt_a = LN(tgt + tmp); xca16 = bf16(tgt_a + qpos)
    hipLaunchKernelGGL(ln_resid16, dim3(3600), b256, 0, stream,
                       tgt, tmp, ln2g, ln2b, tgt_a, qpos, xca16);
    // 5. fused sampling-offset + attention-weight GEMMs
    hipLaunchKernelGGL(offaw16, dim3(57, 6), b256, 0, stream,
                       xca16, off_w, off_b, aw_w, aw_b, off_raw, aw_raw);
    // 6. deformable sampling (bf16 out)
    hipLaunchKernelGGL(msdeform16, dim3(3600), b256, 0, stream,
                       off_raw, aw_raw, refp, value16, att2_16);
    // 7. oproj -> tmp
    hipLaunchKernelGGL(gemm16_f32, dim3(57, 4), b256, 0, stream,
                       att2_16, op_w, op_b, tmp, NROW, 256, 256, 256);
    // 8. LN1: tgt_b = LN(tgt_a + tmp); tgtb16 = bf16(tgt_b)
    hipLaunchKernelGGL(ln_resid16, dim3(3600), b256, 0, stream,
                       tgt_a, tmp, ln1g, ln1b, tgt_b, (const float*)nullptr, tgtb16);
    // 9. FFN1 + ReLU (bf16 out)
    hipLaunchKernelGGL(gemm16_16, dim3(57, 16), b256, 0, stream,
                       tgtb16, l1w, l1b, hidden16, NROW, 1024, 256, 1024, 1);
    // 10. FFN2 -> tmp
    hipLaunchKernelGGL(gemm16_f32, dim3(57, 4), b256, 0, stream,
                       hidden16, l2w, l2b, tmp, NROW, 256, 1024, 256);
    // 11. LN3 -> d_out
    hipLaunchKernelGGL(ln_resid16, dim3(3600), b256, 0, stream,
                       tgt_b, tmp, ln3g, ln3b, out, (const float*)nullptr, (ushort_t*)nullptr);
}

// Round 10
// 276.329 us; speedup vs baseline: 1.4691x; 1.0579x over previous
//
#include <hip/hip_runtime.h>
#include <math.h>

#define D_MODEL 256
#define NHEAD   8
#define NLVL    4
#define NPTS    4
#define DHEAD   32
#define DFFN    1024
#define NQ      900
#define BSZ     4
#define NROW    (NQ * BSZ)      // 3600
#define S_TOT   11253
#define VROWS   (S_TOT * BSZ)   // 45012
#define SASCALE 0.17677669529663687f

typedef __attribute__((ext_vector_type(8))) short short8;
typedef __attribute__((ext_vector_type(4))) float f32x4;
typedef unsigned short ushort_t;

static __device__ __forceinline__ unsigned f2bf1(float f) {
    unsigned u = __float_as_uint(f);
    return (u + 0x7FFFu + ((u >> 16) & 1u)) >> 16;
}
static __device__ __forceinline__ unsigned pack2bf(float x, float y) {
    return f2bf1(x) | (f2bf1(y) << 16);
}
static __device__ __forceinline__ float bf2f(ushort_t u) {
    return __uint_as_float(((unsigned)u) << 16);
}

#define GPAD 72

// bf16 weight buffer element offsets
#define WB_IN   0         // 768*256
#define WB_VP   196608    // 256*256
#define WB_OUTP 262144    // 256*256
#define WB_OFF  327680    // 256*256
#define WB_AW   393216    // 128*256
#define WB_OP   425984    // 256*256
#define WB_L1   491520    // 1024*256
#define WB_L2   753664    // 256*1024
#define WB_TOT  1015808

// ---------------------------------------------------------------------------
// One-shot fp32 -> bf16 conversion of all weight matrices (2048 elems/block).
// Eliminates the per-block re-conversion that dominated proj_fused (R9 PMC).
// ---------------------------------------------------------------------------
__global__ __launch_bounds__(256) void cvt_weights(
    const float* __restrict__ w_in, const float* __restrict__ w_vp,
    const float* __restrict__ w_outp, const float* __restrict__ w_off,
    const float* __restrict__ w_aw, const float* __restrict__ w_op,
    const float* __restrict__ w_l1, const float* __restrict__ w_l2,
    ushort_t* __restrict__ dst)
{
    int b = blockIdx.x;
    const float* src;
    int dstoff;
    if (b < 96)       { src = w_in;   dstoff = WB_IN;   }
    else if (b < 128) { src = w_vp;   b -= 96;  dstoff = WB_VP;   }
    else if (b < 160) { src = w_outp; b -= 128; dstoff = WB_OUTP; }
    else if (b < 192) { src = w_off;  b -= 160; dstoff = WB_OFF;  }
    else if (b < 208) { src = w_aw;   b -= 192; dstoff = WB_AW;   }
    else if (b < 240) { src = w_op;   b -= 208; dstoff = WB_OP;   }
    else if (b < 368) { src = w_l1;   b -= 240; dstoff = WB_L1;   }
    else              { src = w_l2;   b -= 368; dstoff = WB_L2;   }
    int i = (b * 256 + threadIdx.x) * 8;
    float4 f0 = *(const float4*)(src + i);
    float4 f1 = *(const float4*)(src + i + 4);
    uint4 u;
    u.x = pack2bf(f0.x, f0.y); u.y = pack2bf(f0.z, f0.w);
    u.z = pack2bf(f1.x, f1.y); u.w = pack2bf(f1.z, f1.w);
    *(uint4*)(dst + dstoff + i) = u;
}

// ---------------------------------------------------------------------------
// proj_fused: qkv projection (blocks 0..683) + value projection (684..1387).
// Weights now pre-converted bf16 -> W staging is plain uint4 copies.
// ---------------------------------------------------------------------------
__global__ __launch_bounds__(256) void proj_fused(
    const float* __restrict__ tgt, const float* __restrict__ qpos,
    const ushort_t* __restrict__ in_wb, const float* __restrict__ in_b,
    const float* __restrict__ mem, const ushort_t* __restrict__ vp_wb,
    const float* __restrict__ vp_b,
    ushort_t* __restrict__ qkv16, ushort_t* __restrict__ value16)
{
    __shared__ ushort_t As[64 * GPAD];
    __shared__ ushort_t Ws[256 * GPAD];

    const int t    = threadIdx.x;
    const int bid  = blockIdx.x;
    const int trow = t >> 2;
    const int tk   = (t & 3) << 4;
    const int wv   = t >> 6;
    const int ln   = t & 63;
    const int L    = ln & 15;
    const int quad = ln >> 4;

    if (bid < 684) {
        // ---------------- QKV path ----------------
        const int m0 = (bid % 57) * 64;
        const int n0 = (bid / 57) * 64;
        const bool addpos = (n0 < 512);
        const float oscale = (n0 < 256) ? SASCALE : 1.f;

        f32x4 acc[4] = {{0.f,0.f,0.f,0.f},{0.f,0.f,0.f,0.f},
                        {0.f,0.f,0.f,0.f},{0.f,0.f,0.f,0.f}};

        for (int k0 = 0; k0 < 256; k0 += 64) {
            {
                int m = m0 + trow;
                float4 a0, a1, a2, a3;
                if (m < NROW) {
                    const float* ap = tgt + (size_t)m * 256 + k0 + tk;
                    a0 = *(const float4*)(ap + 0);
                    a1 = *(const float4*)(ap + 4);
                    a2 = *(const float4*)(ap + 8);
                    a3 = *(const float4*)(ap + 12);
                    if (addpos) {
                        const float* pp = qpos + (size_t)m * 256 + k0 + tk;
                        float4 p0 = *(const float4*)(pp + 0);
                        float4 p1 = *(const float4*)(pp + 4);
                        float4 p2 = *(const float4*)(pp + 8);
                        float4 p3 = *(const float4*)(pp + 12);
                        a0.x += p0.x; a0.y += p0.y; a0.z += p0.z; a0.w += p0.w;
                        a1.x += p1.x; a1.y += p1.y; a1.z += p1.z; a1.w += p1.w;
                        a2.x += p2.x; a2.y += p2.y; a2.z += p2.z; a2.w += p2.w;
                        a3.x += p3.x; a3.y += p3.y; a3.z += p3.z; a3.w += p3.w;
                    }
                } else {
                    a0 = a1 = a2 = a3 = make_float4(0.f, 0.f, 0.f, 0.f);
                }
                uint4 u0, u1;
                u0.x = pack2bf(a0.x, a0.y); u0.y = pack2bf(a0.z, a0.w);
                u0.z = pack2bf(a1.x, a1.y); u0.w = pack2bf(a1.z, a1.w);
                u1.x = pack2bf(a2.x, a2.y); u1.y = pack2bf(a2.z, a2.w);
                u1.z = pack2bf(a3.x, a3.y); u1.w = pack2bf(a3.z, a3.w);
                *(uint4*)&As[trow * GPAD + tk + 0] = u0;
                *(uint4*)&As[trow * GPAD + tk + 8] = u1;
            }
            {
                int n = n0 + trow;
                const ushort_t* wp = in_wb + (size_t)n * 256 + k0 + tk;
                *(uint4*)&Ws[trow * GPAD + tk + 0] = *(const uint4*)(wp + 0);
                *(uint4*)&Ws[trow * GPAD + tk + 8] = *(const uint4*)(wp + 8);
            }
            __syncthreads();
#pragma unroll
            for (int kh = 0; kh < 2; ++kh) {
                short8 af = *(const short8*)&As[(wv * 16 + L) * GPAD + kh * 32 + quad * 8];
#pragma unroll
                for (int cb = 0; cb < 4; ++cb) {
                    short8 bf = *(const short8*)&Ws[(cb * 16 + L) * GPAD + kh * 32 + quad * 8];
                    acc[cb] = __builtin_amdgcn_mfma_f32_16x16x32_bf16(af, bf, acc[cb], 0, 0, 0);
                }
            }
            __syncthreads();
        }
#pragma unroll
        for (int cb = 0; cb < 4; ++cb) {
            int col = n0 + cb * 16 + L;
            float bv = in_b[col];
#pragma unroll
            for (int i = 0; i < 4; ++i) {
                int m = m0 + wv * 16 + quad * 4 + i;
                if (m < NROW)
                    qkv16[(size_t)m * 768 + col] = (ushort_t)f2bf1((acc[cb][i] + bv) * oscale);
            }
        }
    } else {
        // ---------------- value-projection path ----------------
        const int m0 = (bid - 684) * 64;

        f32x4 acc[16];
#pragma unroll
        for (int i = 0; i < 16; ++i) acc[i] = (f32x4){0.f, 0.f, 0.f, 0.f};

        for (int k0 = 0; k0 < 256; k0 += 64) {
            {
                int m = m0 + trow;
                float4 a0, a1, a2, a3;
                if (m < VROWS) {
                    const float* ap = mem + (size_t)m * 256 + k0 + tk;
                    a0 = *(const float4*)(ap + 0);
                    a1 = *(const float4*)(ap + 4);
                    a2 = *(const float4*)(ap + 8);
                    a3 = *(const float4*)(ap + 12);
                } else {
                    a0 = a1 = a2 = a3 = make_float4(0.f, 0.f, 0.f, 0.f);
                }
                uint4 u0, u1;
                u0.x = pack2bf(a0.x, a0.y); u0.y = pack2bf(a0.z, a0.w);
                u0.z = pack2bf(a1.x, a1.y); u0.w = pack2bf(a1.z, a1.w);
                u1.x = pack2bf(a2.x, a2.y); u1.y = pack2bf(a2.z, a2.w);
                u1.z = pack2bf(a3.x, a3.y); u1.w = pack2bf(a3.z, a3.w);
                *(uint4*)&As[trow * GPAD + tk + 0] = u0;
                *(uint4*)&As[trow * GPAD + tk + 8] = u1;
            }
#pragma unroll
            for (int wb = 0; wb < 4; ++wb) {
                int n = wb * 64 + trow;
                const ushort_t* wp = vp_wb + (size_t)n * 256 + k0 + tk;
                *(uint4*)&Ws[n * GPAD + tk + 0] = *(const uint4*)(wp + 0);
                *(uint4*)&Ws[n * GPAD + tk + 8] = *(const uint4*)(wp + 8);
            }
            __syncthreads();
#pragma unroll
            for (int kh = 0; kh < 2; ++kh) {
                short8 af = *(const short8*)&As[(wv * 16 + L) * GPAD + kh * 32 + quad * 8];
#pragma unroll
                for (int cb = 0; cb < 16; ++cb) {
                    short8 bf = *(const short8*)&Ws[(cb * 16 + L) * GPAD + kh * 32 + quad * 8];
                    acc[cb] = __builtin_amdgcn_mfma_f32_16x16x32_bf16(af, bf, acc[cb], 0, 0, 0);
                }
            }
            __syncthreads();
        }

        ushort_t* Cs = Ws;
#pragma unroll
        for (int cb = 0; cb < 16; ++cb) {
            int col = cb * 16 + L;
            float bv = vp_b[col];
#pragma unroll
            for (int i = 0; i < 4; ++i) {
                int r = wv * 16 + quad * 4 + i;
                Cs[r * 264 + col] = (ushort_t)f2bf1(acc[cb][i] + bv);
            }
        }
        __syncthreads();
        {
            int r  = t >> 2;
            int ch = (t & 3) * 64;
            int m  = m0 + r;
            if (m < VROWS) {
                const ushort_t* src = &Cs[r * 264 + ch];
                uint4* dst = (uint4*)(value16 + (size_t)m * 256 + ch);
#pragma unroll
                for (int j = 0; j < 8; ++j)
                    dst[j] = *(const uint4*)(src + j * 8);
            }
        }
    }
}

// ---------------------------------------------------------------------------
// MFMA flash self-attention, bf16 in / bf16 out (unchanged).
// ---------------------------------------------------------------------------
__global__ __launch_bounds__(256) void sa_flash16(
    const ushort_t* __restrict__ qkv, ushort_t* __restrict__ attn_out)
{
    __shared__ ushort_t Ks[2 * 2080];
    __shared__ ushort_t Vt[2 * 2304];
    __shared__ ushort_t Ps[4 * 1152];

    const int t    = threadIdx.x;
    const int q0   = blockIdx.x * 64;
    const int b    = blockIdx.y & 3;
    const int h    = blockIdx.y >> 2;
    const int wv   = t >> 6;
    const int ln   = t & 63;
    const int L    = ln & 15;
    const int quad = ln >> 4;

    union { uint4 u; short8 s; } qu;
    qu.u = make_uint4(0u, 0u, 0u, 0u);
    {
        int q = q0 + wv * 16 + L;
        if (q < NQ)
            qu.u = *(const uint4*)(qkv + ((size_t)q * 4 + b) * 768 + h * 32 + quad * 8);
    }
    const short8 qf = qu.s;

    float mrun = -1e30f, lrun = 0.f;
    f32x4 oacc[2] = {{0.f,0.f,0.f,0.f},{0.f,0.f,0.f,0.f}};

    const int skey = t >> 2;
    const int sdg  = t & 3;

    int it = 0;
    for (int k0 = 0; k0 < NQ; k0 += 64, it ^= 1) {
        {
            int kg = k0 + skey;
            uint4 ku = make_uint4(0u,0u,0u,0u), vu = make_uint4(0u,0u,0u,0u);
            if (kg < NQ) {
                const ushort_t* base = qkv + ((size_t)kg * 4 + b) * 768 + 256 + h * 32 + sdg * 8;
                ku = *(const uint4*)base;
                vu = *(const uint4*)(base + 256);
            }
            *(uint4*)&Ks[it * 2080 + sdg * 520 + skey * 8] = ku;
            ushort_t* vp = &Vt[it * 2304 + sdg * 8 * 72 + skey];
            vp[0 * 72] = (ushort_t)(vu.x & 0xffffu);
            vp[1 * 72] = (ushort_t)(vu.x >> 16);
            vp[2 * 72] = (ushort_t)(vu.y & 0xffffu);
            vp[3 * 72] = (ushort_t)(vu.y >> 16);
            vp[4 * 72] = (ushort_t)(vu.z & 0xffffu);
            vp[5 * 72] = (ushort_t)(vu.z >> 16);
            vp[6 * 72] = (ushort_t)(vu.w & 0xffffu);
            vp[7 * 72] = (ushort_t)(vu.w >> 16);
        }
        __syncthreads();

        f32x4 sacc[4] = {{0.f,0.f,0.f,0.f},{0.f,0.f,0.f,0.f},
                         {0.f,0.f,0.f,0.f},{0.f,0.f,0.f,0.f}};
#pragma unroll
        for (int cb = 0; cb < 4; ++cb) {
            short8 kf = *(const short8*)&Ks[it * 2080 + quad * 520 + (cb * 16 + L) * 8];
            sacc[cb] = __builtin_amdgcn_mfma_f32_16x16x32_bf16(kf, qf, sacc[cb], 0, 0, 0);
        }
        if (k0 + 64 > NQ) {
#pragma unroll
            for (int cb = 0; cb < 4; ++cb)
#pragma unroll
                for (int i = 0; i < 4; ++i)
                    if (k0 + cb * 16 + quad * 4 + i >= NQ) sacc[cb][i] = -1e30f;
        }

        float ml = -1e30f;
#pragma unroll
        for (int cb = 0; cb < 4; ++cb)
#pragma unroll
            for (int i = 0; i < 4; ++i) ml = fmaxf(ml, sacc[cb][i]);
        ml = fmaxf(ml, __shfl_xor(ml, 16, 64));
        ml = fmaxf(ml, __shfl_xor(ml, 32, 64));
        float mnew  = fmaxf(mrun, ml);
        float alpha = __expf(mrun - mnew);
        float p[16];
        float rs = 0.f;
#pragma unroll
        for (int cb = 0; cb < 4; ++cb)
#pragma unroll
            for (int i = 0; i < 4; ++i) {
                float e = __expf(sacc[cb][i] - mnew);
                p[cb * 4 + i] = e;
                rs += e;
            }
        rs += __shfl_xor(rs, 16, 64);
        rs += __shfl_xor(rs, 32, 64);
        lrun = lrun * alpha + rs;
        mrun = mnew;

        {
            ushort_t* pw = &Ps[wv * 1152 + L * 72];
#pragma unroll
            for (int cb = 0; cb < 4; ++cb) {
                uint2 u;
                u.x = pack2bf(p[cb * 4 + 0], p[cb * 4 + 1]);
                u.y = pack2bf(p[cb * 4 + 2], p[cb * 4 + 3]);
                *(uint2*)&pw[cb * 16 + quad * 4] = u;
            }
        }
#pragma unroll
        for (int i = 0; i < 4; ++i) {
            float ai = __shfl(alpha, quad * 4 + i, 64);
            oacc[0][i] *= ai;
            oacc[1][i] *= ai;
        }
        __syncthreads();

#pragma unroll
        for (int ks = 0; ks < 2; ++ks) {
            short8 pf = *(const short8*)&Ps[wv * 1152 + L * 72 + ks * 32 + quad * 8];
#pragma unroll
            for (int db = 0; db < 2; ++db) {
                short8 vf = *(const short8*)&Vt[it * 2304 + (db * 16 + L) * 72 + ks * 32 + quad * 8];
                oacc[db] = __builtin_amdgcn_mfma_f32_16x16x32_bf16(pf, vf, oacc[db], 0, 0, 0);
            }
        }
    }

#pragma unroll
    for (int i = 0; i < 4; ++i) {
        float lq = __shfl(lrun, quad * 4 + i, 64);
        float li = 1.f / lq;
        int q = q0 + wv * 16 + quad * 4 + i;
        if (q < NQ) {
            ushort_t* op = attn_out + ((size_t)q * 4 + b) * 256 + h * 32 + L;
            op[0]  = (ushort_t)f2bf1(oacc[0][i] * li);
            op[16] = (ushort_t)f2bf1(oacc[1][i] * li);
        }
    }
}

// ---------------------------------------------------------------------------
// Plain 64x64-tile GEMM, bf16 A, bf16 W (pre-converted), fp32 C.
// ---------------------------------------------------------------------------
__global__ __launch_bounds__(256) void gemm16_f32(
    const ushort_t* __restrict__ A, const ushort_t* __restrict__ W,
    const float* __restrict__ bias, float* __restrict__ C,
    int M, int N, int K, int ldc)
{
    __shared__ ushort_t As[64 * GPAD];
    __shared__ ushort_t Ws[64 * GPAD];

    const int t  = threadIdx.x;
    const int m0 = blockIdx.x * 64;
    const int n0 = blockIdx.y * 64;
    const int trow = t >> 2;
    const int tk   = (t & 3) << 4;
    const int wv   = t >> 6;
    const int ln   = t & 63;
    const int L    = ln & 15;
    const int quad = ln >> 4;

    f32x4 acc[4] = {{0.f,0.f,0.f,0.f},{0.f,0.f,0.f,0.f},
                    {0.f,0.f,0.f,0.f},{0.f,0.f,0.f,0.f}};

    for (int k0 = 0; k0 < K; k0 += 64) {
        {
            int m = m0 + trow;
            uint4 a0 = make_uint4(0u,0u,0u,0u), a1 = make_uint4(0u,0u,0u,0u);
            if (m < M) {
                const ushort_t* ap = A + (size_t)m * K + k0 + tk;
                a0 = *(const uint4*)ap;
                a1 = *(const uint4*)(ap + 8);
            }
            *(uint4*)&As[trow * GPAD + tk + 0] = a0;
            *(uint4*)&As[trow * GPAD + tk + 8] = a1;
        }
        {
            int n = n0 + trow;
            const ushort_t* wp = W + (size_t)n * K + k0 + tk;
            *(uint4*)&Ws[trow * GPAD + tk + 0] = *(const uint4*)(wp + 0);
            *(uint4*)&Ws[trow * GPAD + tk + 8] = *(const uint4*)(wp + 8);
        }
        __syncthreads();
#pragma unroll
        for (int kh = 0; kh < 2; ++kh) {
            short8 af = *(const short8*)&As[(wv * 16 + L) * GPAD + kh * 32 + quad * 8];
#pragma unroll
            for (int cb = 0; cb < 4; ++cb) {
                short8 bf = *(const short8*)&Ws[(cb * 16 + L) * GPAD + kh * 32 + quad * 8];
                acc[cb] = __builtin_amdgcn_mfma_f32_16x16x32_bf16(af, bf, acc[cb], 0, 0, 0);
            }
        }
        __syncthreads();
    }
#pragma unroll
    for (int cb = 0; cb < 4; ++cb) {
        int col = n0 + cb * 16 + L;
        float bv = bias[col];
#pragma unroll
        for (int i = 0; i < 4; ++i) {
            int m = m0 + wv * 16 + quad * 4 + i;
            if (m < M)
                C[(size_t)m * ldc + col] = acc[cb][i] + bv;
        }
    }
}

// ---------------------------------------------------------------------------
// Residual + LayerNorm + optional bf16 out2(+pos). One block per row.
// ---------------------------------------------------------------------------
__global__ __launch_bounds__(256) void ln_resid16(
    const float* __restrict__ xa, const float* __restrict__ xb,
    const float* __restrict__ gam, const float* __restrict__ bet,
    float* __restrict__ out, const float* __restrict__ pos,
    ushort_t* __restrict__ out2)
{
    const int row = blockIdx.x;
    const int t = threadIdx.x;
    float x = xa[(size_t)row * D_MODEL + t] + xb[(size_t)row * D_MODEL + t];
    float s = x, s2 = x * x;
#pragma unroll
    for (int off = 32; off > 0; off >>= 1) {
        s  += __shfl_down(s, off, 64);
        s2 += __shfl_down(s2, off, 64);
    }
    __shared__ float rs[4], rs2[4];
    __shared__ float mean_s, rstd_s;
    int wid = t >> 6, lane = t & 63;
    if (lane == 0) { rs[wid] = s; rs2[wid] = s2; }
    __syncthreads();
    if (t == 0) {
        float S = rs[0] + rs[1] + rs[2] + rs[3];
        float S2 = rs2[0] + rs2[1] + rs2[2] + rs2[3];
        float mean = S * (1.f / 256.f);
        float var = S2 * (1.f / 256.f) - mean * mean;
        mean_s = mean;
        rstd_s = rsqrtf(var + 1e-5f);
    }
    __syncthreads();
    float y = (x - mean_s) * rstd_s * gam[t] + bet[t];
    out[(size_t)row * D_MODEL + t] = y;
    if (out2) {
        float o2 = y + (pos ? pos[(size_t)row * D_MODEL + t] : 0.f);
        out2[(size_t)row * D_MODEL + t] = (ushort_t)f2bf1(o2);
    }
}

// ---------------------------------------------------------------------------
// Fused offset + attention-weight GEMM (bf16 weights).
// ---------------------------------------------------------------------------
__global__ __launch_bounds__(256) void offaw16(
    const ushort_t* __restrict__ A,
    const ushort_t* __restrict__ off_wb, const float* __restrict__ off_b,
    const ushort_t* __restrict__ aw_wb, const float* __restrict__ aw_b,
    float* __restrict__ off_raw, float* __restrict__ aw_raw)
{
    __shared__ ushort_t As[64 * GPAD];
    __shared__ ushort_t Ws[64 * GPAD];

    const int t  = threadIdx.x;
    const int m0 = blockIdx.x * 64;
    const int by = blockIdx.y;
    const bool isaw = (by >= 4);
    const int n0 = isaw ? (by - 4) * 64 : by * 64;
    const ushort_t* W = isaw ? aw_wb : off_wb;
    const float* bs = isaw ? aw_b : off_b;
    float* C = isaw ? aw_raw : off_raw;
    const int ldc = isaw ? 128 : 256;

    const int trow = t >> 2;
    const int tk   = (t & 3) << 4;
    const int wv   = t >> 6;
    const int ln   = t & 63;
    const int L    = ln & 15;
    const int quad = ln >> 4;

    f32x4 acc[4] = {{0.f,0.f,0.f,0.f},{0.f,0.f,0.f,0.f},
                    {0.f,0.f,0.f,0.f},{0.f,0.f,0.f,0.f}};

    for (int k0 = 0; k0 < 256; k0 += 64) {
        {
            int m = m0 + trow;
            uint4 a0 = make_uint4(0u,0u,0u,0u), a1 = make_uint4(0u,0u,0u,0u);
            if (m < NROW) {
                const ushort_t* ap = A + (size_t)m * 256 + k0 + tk;
                a0 = *(const uint4*)ap;
                a1 = *(const uint4*)(ap + 8);
            }
            *(uint4*)&As[trow * GPAD + tk + 0] = a0;
            *(uint4*)&As[trow * GPAD + tk + 8] = a1;
        }
        {
            int n = n0 + trow;
            const ushort_t* wp = W + (size_t)n * 256 + k0 + tk;
            *(uint4*)&Ws[trow * GPAD + tk + 0] = *(const uint4*)(wp + 0);
            *(uint4*)&Ws[trow * GPAD + tk + 8] = *(const uint4*)(wp + 8);
        }
        __syncthreads();
#pragma unroll
        for (int kh = 0; kh < 2; ++kh) {
            short8 af = *(const short8*)&As[(wv * 16 + L) * GPAD + kh * 32 + quad * 8];
#pragma unroll
            for (int cb = 0; cb < 4; ++cb) {
                short8 bf = *(const short8*)&Ws[(cb * 16 + L) * GPAD + kh * 32 + quad * 8];
                acc[cb] = __builtin_amdgcn_mfma_f32_16x16x32_bf16(af, bf, acc[cb], 0, 0, 0);
            }
        }
        __syncthreads();
    }
#pragma unroll
    for (int cb = 0; cb < 4; ++cb) {
        int col = n0 + cb * 16 + L;
        float bv = bs[col];
#pragma unroll
        for (int i = 0; i < 4; ++i) {
            int m = m0 + wv * 16 + quad * 4 + i;
            if (m < NROW)
                C[(size_t)m * ldc + col] = acc[cb][i] + bv;
        }
    }
}

// ---------------------------------------------------------------------------
// Generic A-bf16, W-bf16 -> C-bf16 GEMM (FFN1 with ReLU).
// ---------------------------------------------------------------------------
__global__ __launch_bounds__(256) void gemm16_16(
    const ushort_t* __restrict__ A, const ushort_t* __restrict__ W,
    const float* __restrict__ bias, ushort_t* __restrict__ C,
    int M, int N, int K, int ldc, int relu)
{
    __shared__ ushort_t As[64 * GPAD];
    __shared__ ushort_t Ws[64 * GPAD];

    const int t  = threadIdx.x;
    const int m0 = blockIdx.x * 64;
    const int n0 = blockIdx.y * 64;
    const int trow = t >> 2;
    const int tk   = (t & 3) << 4;
    const int wv   = t >> 6;
    const int ln   = t & 63;
    const int L    = ln & 15;
    const int quad = ln >> 4;

    f32x4 acc[4] = {{0.f,0.f,0.f,0.f},{0.f,0.f,0.f,0.f},
                    {0.f,0.f,0.f,0.f},{0.f,0.f,0.f,0.f}};

    for (int k0 = 0; k0 < K; k0 += 64) {
        {
            int m = m0 + trow;
            uint4 a0 = make_uint4(0u,0u,0u,0u), a1 = make_uint4(0u,0u,0u,0u);
            if (m < M) {
                const ushort_t* ap = A + (size_t)m * K + k0 + tk;
                a0 = *(const uint4*)ap;
                a1 = *(const uint4*)(ap + 8);
            }
            *(uint4*)&As[trow * GPAD + tk + 0] = a0;
            *(uint4*)&As[trow * GPAD + tk + 8] = a1;
        }
        {
            int n = n0 + trow;
            const ushort_t* wp = W + (size_t)n * K + k0 + tk;
            *(uint4*)&Ws[trow * GPAD + tk + 0] = *(const uint4*)(wp + 0);
            *(uint4*)&Ws[trow * GPAD + tk + 8] = *(const uint4*)(wp + 8);
        }
        __syncthreads();
#pragma unroll
        for (int kh = 0; kh < 2; ++kh) {
            short8 af = *(const short8*)&As[(wv * 16 + L) * GPAD + kh * 32 + quad * 8];
#pragma unroll
            for (int cb = 0; cb < 4; ++cb) {
                short8 bf = *(const short8*)&Ws[(cb * 16 + L) * GPAD + kh * 32 + quad * 8];
                acc[cb] = __builtin_amdgcn_mfma_f32_16x16x32_bf16(af, bf, acc[cb], 0, 0, 0);
            }
        }
        __syncthreads();
    }
#pragma unroll
    for (int cb = 0; cb < 4; ++cb) {
        int col = n0 + cb * 16 + L;
        float bv = bias[col];
#pragma unroll
        for (int i = 0; i < 4; ++i) {
            int m = m0 + wv * 16 + quad * 4 + i;
            if (m < M) {
                float o = acc[cb][i] + bv;
                if (relu) o = fmaxf(o, 0.f);
                C[(size_t)m * ldc + col] = (ushort_t)f2bf1(o);
            }
        }
    }
}

// ---------------------------------------------------------------------------
// Multi-scale deformable sampling (unchanged).
// ---------------------------------------------------------------------------
__global__ __launch_bounds__(256) void msdeform16(
    const float* __restrict__ off_raw, const float* __restrict__ aw_raw,
    const float* __restrict__ refp, const ushort_t* __restrict__ value,
    ushort_t* __restrict__ out)
{
    const int row = blockIdx.x;   // q*4+b
    const int b = row & 3;
    const int t = threadIdx.x;

    __shared__ float aw_s[8][17];
    __shared__ float px_s[8][16];
    __shared__ float py_s[8][16];

    const int Hs[4]  = {92, 46, 23, 12};
    const int Wd[4]  = {92, 46, 23, 12};
    const int S0_[4] = {0, 8464, 10580, 11109};

    if (t < 128) {
        int hh = t >> 4, lp = t & 15, l = lp >> 2;
        float ox = off_raw[(size_t)row * 256 + hh * 32 + lp * 2 + 0];
        float oy = off_raw[(size_t)row * 256 + hh * 32 + lp * 2 + 1];
        float rx = refp[((size_t)row * 4 + l) * 2 + 0];
        float ry = refp[((size_t)row * 4 + l) * 2 + 1];
        px_s[hh][lp] = rx * (float)Wd[l] + ox - 0.5f;
        py_s[hh][lp] = ry * (float)Hs[l] + oy - 0.5f;
    }
    if (t < 8) {
        int hh = t;
        float v[16];
        float m = -1e30f;
#pragma unroll
        for (int j = 0; j < 16; ++j) {
            v[j] = aw_raw[(size_t)row * 128 + hh * 16 + j];
            m = fmaxf(m, v[j]);
        }
        float ssum = 0.f;
#pragma unroll
        for (int j = 0; j < 16; ++j) { v[j] = __expf(v[j] - m); ssum += v[j]; }
        float inv = 1.f / ssum;
#pragma unroll
        for (int j = 0; j < 16; ++j) aw_s[hh][j] = v[j] * inv;
    }
    __syncthreads();

    const int h = t >> 5, d = t & 31;
    const ushort_t* vb = value + (size_t)b * 256 + h * 32 + d;
    float acc = 0.f;
#pragma unroll
    for (int l = 0; l < 4; ++l) {
        const int H = Hs[l], W = Wd[l], base = S0_[l];
#pragma unroll
        for (int p = 0; p < 4; ++p) {
            const int lp = l * 4 + p;
            float px = px_s[h][lp], py = py_s[h][lp];
            float x0f = floorf(px), y0f = floorf(py);
            int x0 = (int)x0f, y0 = (int)y0f;
            float wx = px - x0f, wy = py - y0f;
            float sv = 0.f;
#pragma unroll
            for (int dy = 0; dy < 2; ++dy) {
#pragma unroll
                for (int dx = 0; dx < 2; ++dx) {
                    int xi = x0 + dx, yi = y0 + dy;
                    float flag = (xi >= 0 && xi < W && yi >= 0 && yi < H) ? 1.f : 0.f;
                    int xc = xi < 0 ? 0 : (xi >= W ? W - 1 : xi);
                    int yc = yi < 0 ? 0 : (yi >= H ? H - 1 : yi);
                    float wgt = (dx ? wx : 1.f - wx) * (dy ? wy : 1.f - wy);
                    float gv = bf2f(vb[(size_t)(base + yc * W + xc) * 1024]);
                    sv = fmaf(wgt * flag, gv, sv);
                }
            }
            acc = fmaf(aw_s[h][lp], sv, acc);
        }
    }
    out[(size_t)row * 256 + h * 32 + d] = (ushort_t)f2bf1(acc);
}

// ---------------------------------------------------------------------------
extern "C" void kernel_launch(void* const* d_in, const int* in_sizes, int n_in,
                              void* d_out, int out_size, void* d_ws, size_t ws_size,
                              hipStream_t stream)
{
    const float* tgt    = (const float*)d_in[0];
    const float* qpos   = (const float*)d_in[1];
    const float* refp   = (const float*)d_in[2];
    const float* mem    = (const float*)d_in[3];
    const float* in_w   = (const float*)d_in[6];
    const float* in_b   = (const float*)d_in[7];
    const float* outp_w = (const float*)d_in[8];
    const float* outp_b = (const float*)d_in[9];
    const float* off_w  = (const float*)d_in[10];
    const float* off_b  = (const float*)d_in[11];
    const float* aw_w   = (const float*)d_in[12];
    const float* aw_b   = (const float*)d_in[13];
    const float* vp_w   = (const float*)d_in[14];
    const float* vp_b   = (const float*)d_in[15];
    const float* op_w   = (const float*)d_in[16];
    const float* op_b   = (const float*)d_in[17];
    const float* ln1g   = (const float*)d_in[18];
    const float* ln1b   = (const float*)d_in[19];
    const float* ln2g   = (const float*)d_in[20];
    const float* ln2b   = (const float*)d_in[21];
    const float* ln3g   = (const float*)d_in[22];
    const float* ln3b   = (const float*)d_in[23];
    const float* l1w    = (const float*)d_in[24];
    const float* l1b    = (const float*)d_in[25];
    const float* l2w    = (const float*)d_in[26];
    const float* l2b    = (const float*)d_in[27];
    float* out = (float*)d_out;
    float* ws  = (float*)d_ws;

    // workspace layout (float units)
    ushort_t* qkv16    = (ushort_t*)ws;                 // 691200 floats
    ushort_t* att16    = (ushort_t*)(ws + 691200);      // 230400
    float*    tmp      = ws + 921600;                   // 921600
    float*    tgt_a    = ws + 1843200;                  // 921600
    ushort_t* xca16    = (ushort_t*)(ws + 2764800);     // 230400
    float*    off_raw  = ws + 2995200;                  // 921600
    float*    aw_raw   = ws + 3916800;                  // 460800
    ushort_t* att2_16  = (ushort_t*)(ws + 4377600);     // 230400
    float*    tgt_b    = ws + 4608000;                  // 921600
    ushort_t* tgtb16   = (ushort_t*)(ws + 5529600);     // 230400
    ushort_t* value16  = (ushort_t*)(ws + 5760000);     // 5761536
    ushort_t* hidden16 = (ushort_t*)(ws + 11521536);    // 1843200
    ushort_t* wb       = (ushort_t*)(ws + 13364736);    // 507904 (bf16 weights)

    const ushort_t* in_wb   = wb + WB_IN;
    const ushort_t* vp_wb   = wb + WB_VP;
    const ushort_t* outp_wb = wb + WB_OUTP;
    const ushort_t* off_wb  = wb + WB_OFF;
    const ushort_t* aw_wb   = wb + WB_AW;
    const ushort_t* op_wb   = wb + WB_OP;
    const ushort_t* l1_wb   = wb + WB_L1;
    const ushort_t* l2_wb   = wb + WB_L2;

    dim3 b256(256);

    // 0. one-shot weight conversion fp32 -> bf16
    hipLaunchKernelGGL(cvt_weights, dim3(496), b256, 0, stream,
                       in_w, vp_w, outp_w, off_w, aw_w, op_w, l1w, l2w, wb);
    // 1. qkv + value projection (independent -> one dispatch)
    hipLaunchKernelGGL(proj_fused, dim3(1388), b256, 0, stream,
                       tgt, qpos, in_wb, in_b, mem, vp_wb, vp_b, qkv16, value16);
    // 2. flash self-attention
    hipLaunchKernelGGL(sa_flash16, dim3(15, 32), b256, 0, stream, qkv16, att16);
    // 3. out-proj -> tmp (fp32)
    hipLaunchKernelGGL(gemm16_f32, dim3(57, 4), b256, 0, stream,
                       att16, outp_wb, outp_b, tmp, NROW, 256, 256, 256);
    // 4. LN2: tgt_a = LN(tgt + tmp); xca16 = bf16(tgt_a + qpos)
    hipLaunchKernelGGL(ln_resid16, dim3(3600), b256, 0, stream,
                       tgt, tmp, ln2g, ln2b, tgt_a, qpos, xca16);
    // 5. fused sampling-offset + attention-weight GEMMs
    hipLaunchKernelGGL(offaw16, dim3(57, 6), b256, 0, stream,
                       xca16, off_wb, off_b, aw_wb, aw_b, off_raw, aw_raw);
    // 6. deformable sampling (bf16 out)
    hipLaunchKernelGGL(msdeform16, dim3(3600), b256, 0, stream,
                       off_raw, aw_raw, refp, value16, att2_16);
    // 7. oproj -> tmp
    hipLaunchKernelGGL(gemm16_f32, dim3(57, 4), b256, 0, stream,
                       att2_16, op_wb, op_b, tmp, NROW, 256, 256, 256);
    // 8. LN1: tgt_b = LN(tgt_a + tmp); tgtb16 = bf16(tgt_b)
    hipLaunchKernelGGL(ln_resid16, dim3(3600), b256, 0, stream,
                       tgt_a, tmp, ln1g, ln1b, tgt_b, (const float*)nullptr, tgtb16);
    // 9. FFN1 + ReLU (bf16 out)
    hipLaunchKernelGGL(gemm16_16, dim3(57, 16), b256, 0, stream,
                       tgtb16, l1_wb, l1b, hidden16, NROW, 1024, 256, 1024, 1);
    // 10. FFN2 -> tmp
    hipLaunchKernelGGL(gemm16_f32, dim3(57, 4), b256, 0, stream,
                       hidden16, l2_wb, l2b, tmp, NROW, 256, 1024, 256);
    // 11. LN3 -> d_out
    hipLaunchKernelGGL(ln_resid16, dim3(3600), b256, 0, stream,
                       tgt_b, tmp, ln3g, ln3b, out, (const float*)nullptr, (ushort_t*)nullptr);
}

// Round 11
// 273.838 us; speedup vs baseline: 1.4824x; 1.0091x over previous
//
#include <hip/hip_runtime.h>
#include <math.h>

#define D_MODEL 256
#define NHEAD   8
#define NLVL    4
#define NPTS    4
#define DHEAD   32
#define DFFN    1024
#define NQ      900
#define BSZ     4
#define NROW    (NQ * BSZ)      // 3600
#define S_TOT   11253
#define VROWS   (S_TOT * BSZ)   // 45012
#define SASCALE 0.17677669529663687f

typedef __attribute__((ext_vector_type(8))) short short8;
typedef __attribute__((ext_vector_type(4))) float f32x4;
typedef unsigned short ushort_t;

static __device__ __forceinline__ unsigned f2bf1(float f) {
    unsigned u = __float_as_uint(f);
    return (u + 0x7FFFu + ((u >> 16) & 1u)) >> 16;
}
static __device__ __forceinline__ unsigned pack2bf(float x, float y) {
    return f2bf1(x) | (f2bf1(y) << 16);
}
static __device__ __forceinline__ float bf2f(ushort_t u) {
    return __uint_as_float(((unsigned)u) << 16);
}

#define GPAD 72

// bf16 weight buffer element offsets
#define WB_IN   0         // 768*256
#define WB_VP   196608    // 256*256
#define WB_OUTP 262144    // 256*256
#define WB_OFF  327680    // 256*256
#define WB_AW   393216    // 128*256
#define WB_OP   425984    // 256*256
#define WB_L1   491520    // 1024*256
#define WB_L2   753664    // 256*1024
#define WB_TOT  1015808

// ---------------------------------------------------------------------------
// One-shot fp32 -> bf16 conversion of all weight matrices.
// ---------------------------------------------------------------------------
__global__ __launch_bounds__(256) void cvt_weights(
    const float* __restrict__ w_in, const float* __restrict__ w_vp,
    const float* __restrict__ w_outp, const float* __restrict__ w_off,
    const float* __restrict__ w_aw, const float* __restrict__ w_op,
    const float* __restrict__ w_l1, const float* __restrict__ w_l2,
    ushort_t* __restrict__ dst)
{
    int b = blockIdx.x;
    const float* src;
    int dstoff;
    if (b < 96)       { src = w_in;   dstoff = WB_IN;   }
    else if (b < 128) { src = w_vp;   b -= 96;  dstoff = WB_VP;   }
    else if (b < 160) { src = w_outp; b -= 128; dstoff = WB_OUTP; }
    else if (b < 192) { src = w_off;  b -= 160; dstoff = WB_OFF;  }
    else if (b < 208) { src = w_aw;   b -= 192; dstoff = WB_AW;   }
    else if (b < 240) { src = w_op;   b -= 208; dstoff = WB_OP;   }
    else if (b < 368) { src = w_l1;   b -= 240; dstoff = WB_L1;   }
    else              { src = w_l2;   b -= 368; dstoff = WB_L2;   }
    int i = (b * 256 + threadIdx.x) * 8;
    float4 f0 = *(const float4*)(src + i);
    float4 f1 = *(const float4*)(src + i + 4);
    uint4 u;
    u.x = pack2bf(f0.x, f0.y); u.y = pack2bf(f0.z, f0.w);
    u.z = pack2bf(f1.x, f1.y); u.w = pack2bf(f1.z, f1.w);
    *(uint4*)(dst + dstoff + i) = u;
}

// ---------------------------------------------------------------------------
// proj_fused: qkv projection (blocks 0..683) + value projection (684..2091).
// vproj now N-split in half (128 cols/block): LDS 27.6 KB -> 5 blocks/CU
// (was 46 KB -> 3 blocks/CU, latency-bound at 2 TB/s per R10 PMC).
// ---------------------------------------------------------------------------
__global__ __launch_bounds__(256) void proj_fused(
    const float* __restrict__ tgt, const float* __restrict__ qpos,
    const ushort_t* __restrict__ in_wb, const float* __restrict__ in_b,
    const float* __restrict__ mem, const ushort_t* __restrict__ vp_wb,
    const float* __restrict__ vp_b,
    ushort_t* __restrict__ qkv16, ushort_t* __restrict__ value16)
{
    __shared__ ushort_t As[64 * GPAD];    // 9216 B
    __shared__ ushort_t Ws[128 * GPAD];   // 18432 B

    const int t    = threadIdx.x;
    const int bid  = blockIdx.x;
    const int trow = t >> 2;
    const int tk   = (t & 3) << 4;
    const int wv   = t >> 6;
    const int ln   = t & 63;
    const int L    = ln & 15;
    const int quad = ln >> 4;

    if (bid < 684) {
        // ---------------- QKV path (proven 64x64 shape) ----------------
        const int m0 = (bid % 57) * 64;
        const int n0 = (bid / 57) * 64;
        const bool addpos = (n0 < 512);
        const float oscale = (n0 < 256) ? SASCALE : 1.f;

        f32x4 acc[4] = {{0.f,0.f,0.f,0.f},{0.f,0.f,0.f,0.f},
                        {0.f,0.f,0.f,0.f},{0.f,0.f,0.f,0.f}};

        for (int k0 = 0; k0 < 256; k0 += 64) {
            {
                int m = m0 + trow;
                float4 a0, a1, a2, a3;
                if (m < NROW) {
                    const float* ap = tgt + (size_t)m * 256 + k0 + tk;
                    a0 = *(const float4*)(ap + 0);
                    a1 = *(const float4*)(ap + 4);
                    a2 = *(const float4*)(ap + 8);
                    a3 = *(const float4*)(ap + 12);
                    if (addpos) {
                        const float* pp = qpos + (size_t)m * 256 + k0 + tk;
                        float4 p0 = *(const float4*)(pp + 0);
                        float4 p1 = *(const float4*)(pp + 4);
                        float4 p2 = *(const float4*)(pp + 8);
                        float4 p3 = *(const float4*)(pp + 12);
                        a0.x += p0.x; a0.y += p0.y; a0.z += p0.z; a0.w += p0.w;
                        a1.x += p1.x; a1.y += p1.y; a1.z += p1.z; a1.w += p1.w;
                        a2.x += p2.x; a2.y += p2.y; a2.z += p2.z; a2.w += p2.w;
                        a3.x += p3.x; a3.y += p3.y; a3.z += p3.z; a3.w += p3.w;
                    }
                } else {
                    a0 = a1 = a2 = a3 = make_float4(0.f, 0.f, 0.f, 0.f);
                }
                uint4 u0, u1;
                u0.x = pack2bf(a0.x, a0.y); u0.y = pack2bf(a0.z, a0.w);
                u0.z = pack2bf(a1.x, a1.y); u0.w = pack2bf(a1.z, a1.w);
                u1.x = pack2bf(a2.x, a2.y); u1.y = pack2bf(a2.z, a2.w);
                u1.z = pack2bf(a3.x, a3.y); u1.w = pack2bf(a3.z, a3.w);
                *(uint4*)&As[trow * GPAD + tk + 0] = u0;
                *(uint4*)&As[trow * GPAD + tk + 8] = u1;
            }
            {
                int n = n0 + trow;
                const ushort_t* wp = in_wb + (size_t)n * 256 + k0 + tk;
                *(uint4*)&Ws[trow * GPAD + tk + 0] = *(const uint4*)(wp + 0);
                *(uint4*)&Ws[trow * GPAD + tk + 8] = *(const uint4*)(wp + 8);
            }
            __syncthreads();
#pragma unroll
            for (int kh = 0; kh < 2; ++kh) {
                short8 af = *(const short8*)&As[(wv * 16 + L) * GPAD + kh * 32 + quad * 8];
#pragma unroll
                for (int cb = 0; cb < 4; ++cb) {
                    short8 bf = *(const short8*)&Ws[(cb * 16 + L) * GPAD + kh * 32 + quad * 8];
                    acc[cb] = __builtin_amdgcn_mfma_f32_16x16x32_bf16(af, bf, acc[cb], 0, 0, 0);
                }
            }
            __syncthreads();
        }
#pragma unroll
        for (int cb = 0; cb < 4; ++cb) {
            int col = n0 + cb * 16 + L;
            float bv = in_b[col];
#pragma unroll
            for (int i = 0; i < 4; ++i) {
                int m = m0 + wv * 16 + quad * 4 + i;
                if (m < NROW)
                    qkv16[(size_t)m * 768 + col] = (ushort_t)f2bf1((acc[cb][i] + bv) * oscale);
            }
        }
    } else {
        // -------- value-projection path: 64 rows x 128 cols per block --------
        const int vb = bid - 684;
        const int m0 = (vb >> 1) * 64;
        const int nh = (vb & 1) * 128;   // column half: 0 or 128

        f32x4 acc[8];
#pragma unroll
        for (int i = 0; i < 8; ++i) acc[i] = (f32x4){0.f, 0.f, 0.f, 0.f};

        for (int k0 = 0; k0 < 256; k0 += 64) {
            {
                int m = m0 + trow;
                float4 a0, a1, a2, a3;
                if (m < VROWS) {
                    const float* ap = mem + (size_t)m * 256 + k0 + tk;
                    a0 = *(const float4*)(ap + 0);
                    a1 = *(const float4*)(ap + 4);
                    a2 = *(const float4*)(ap + 8);
                    a3 = *(const float4*)(ap + 12);
                } else {
                    a0 = a1 = a2 = a3 = make_float4(0.f, 0.f, 0.f, 0.f);
                }
                uint4 u0, u1;
                u0.x = pack2bf(a0.x, a0.y); u0.y = pack2bf(a0.z, a0.w);
                u0.z = pack2bf(a1.x, a1.y); u0.w = pack2bf(a1.z, a1.w);
                u1.x = pack2bf(a2.x, a2.y); u1.y = pack2bf(a2.z, a2.w);
                u1.z = pack2bf(a3.x, a3.y); u1.w = pack2bf(a3.z, a3.w);
                *(uint4*)&As[trow * GPAD + tk + 0] = u0;
                *(uint4*)&As[trow * GPAD + tk + 8] = u1;
            }
#pragma unroll
            for (int wb = 0; wb < 2; ++wb) {
                int n = wb * 64 + trow;
                const ushort_t* wp = vp_wb + (size_t)(nh + n) * 256 + k0 + tk;
                *(uint4*)&Ws[n * GPAD + tk + 0] = *(const uint4*)(wp + 0);
                *(uint4*)&Ws[n * GPAD + tk + 8] = *(const uint4*)(wp + 8);
            }
            __syncthreads();
#pragma unroll
            for (int kh = 0; kh < 2; ++kh) {
                short8 af = *(const short8*)&As[(wv * 16 + L) * GPAD + kh * 32 + quad * 8];
#pragma unroll
                for (int cb = 0; cb < 8; ++cb) {
                    short8 bf = *(const short8*)&Ws[(cb * 16 + L) * GPAD + kh * 32 + quad * 8];
                    acc[cb] = __builtin_amdgcn_mfma_f32_16x16x32_bf16(af, bf, acc[cb], 0, 0, 0);
                }
            }
            __syncthreads();
        }

        // epilogue: bias + bf16, repack through LDS for coalesced stores
        ushort_t* Cs = Ws;   // 64 rows x 136 stride = 8704 shorts (fits 9216)
#pragma unroll
        for (int cb = 0; cb < 8; ++cb) {
            int col = cb * 16 + L;
            float bv = vp_b[nh + col];
#pragma unroll
            for (int i = 0; i < 4; ++i) {
                int r = wv * 16 + quad * 4 + i;
                Cs[r * 136 + col] = (ushort_t)f2bf1(acc[cb][i] + bv);
            }
        }
        __syncthreads();
        {
            int r  = t >> 2;
            int ch = (t & 3) * 32;
            int m  = m0 + r;
            if (m < VROWS) {
                const ushort_t* src = &Cs[r * 136 + ch];
                uint4* dst = (uint4*)(value16 + (size_t)m * 256 + nh + ch);
#pragma unroll
                for (int j = 0; j < 4; ++j)
                    dst[j] = *(const uint4*)(src + j * 8);
            }
        }
    }
}

// ---------------------------------------------------------------------------
// MFMA flash self-attention, bf16 in / bf16 out (unchanged).
// ---------------------------------------------------------------------------
__global__ __launch_bounds__(256) void sa_flash16(
    const ushort_t* __restrict__ qkv, ushort_t* __restrict__ attn_out)
{
    __shared__ ushort_t Ks[2 * 2080];
    __shared__ ushort_t Vt[2 * 2304];
    __shared__ ushort_t Ps[4 * 1152];

    const int t    = threadIdx.x;
    const int q0   = blockIdx.x * 64;
    const int b    = blockIdx.y & 3;
    const int h    = blockIdx.y >> 2;
    const int wv   = t >> 6;
    const int ln   = t & 63;
    const int L    = ln & 15;
    const int quad = ln >> 4;

    union { uint4 u; short8 s; } qu;
    qu.u = make_uint4(0u, 0u, 0u, 0u);
    {
        int q = q0 + wv * 16 + L;
        if (q < NQ)
            qu.u = *(const uint4*)(qkv + ((size_t)q * 4 + b) * 768 + h * 32 + quad * 8);
    }
    const short8 qf = qu.s;

    float mrun = -1e30f, lrun = 0.f;
    f32x4 oacc[2] = {{0.f,0.f,0.f,0.f},{0.f,0.f,0.f,0.f}};

    const int skey = t >> 2;
    const int sdg  = t & 3;

    int it = 0;
    for (int k0 = 0; k0 < NQ; k0 += 64, it ^= 1) {
        {
            int kg = k0 + skey;
            uint4 ku = make_uint4(0u,0u,0u,0u), vu = make_uint4(0u,0u,0u,0u);
            if (kg < NQ) {
                const ushort_t* base = qkv + ((size_t)kg * 4 + b) * 768 + 256 + h * 32 + sdg * 8;
                ku = *(const uint4*)base;
                vu = *(const uint4*)(base + 256);
            }
            *(uint4*)&Ks[it * 2080 + sdg * 520 + skey * 8] = ku;
            ushort_t* vp = &Vt[it * 2304 + sdg * 8 * 72 + skey];
            vp[0 * 72] = (ushort_t)(vu.x & 0xffffu);
            vp[1 * 72] = (ushort_t)(vu.x >> 16);
            vp[2 * 72] = (ushort_t)(vu.y & 0xffffu);
            vp[3 * 72] = (ushort_t)(vu.y >> 16);
            vp[4 * 72] = (ushort_t)(vu.z & 0xffffu);
            vp[5 * 72] = (ushort_t)(vu.z >> 16);
            vp[6 * 72] = (ushort_t)(vu.w & 0xffffu);
            vp[7 * 72] = (ushort_t)(vu.w >> 16);
        }
        __syncthreads();

        f32x4 sacc[4] = {{0.f,0.f,0.f,0.f},{0.f,0.f,0.f,0.f},
                         {0.f,0.f,0.f,0.f},{0.f,0.f,0.f,0.f}};
#pragma unroll
        for (int cb = 0; cb < 4; ++cb) {
            short8 kf = *(const short8*)&Ks[it * 2080 + quad * 520 + (cb * 16 + L) * 8];
            sacc[cb] = __builtin_amdgcn_mfma_f32_16x16x32_bf16(kf, qf, sacc[cb], 0, 0, 0);
        }
        if (k0 + 64 > NQ) {
#pragma unroll
            for (int cb = 0; cb < 4; ++cb)
#pragma unroll
                for (int i = 0; i < 4; ++i)
                    if (k0 + cb * 16 + quad * 4 + i >= NQ) sacc[cb][i] = -1e30f;
        }

        float ml = -1e30f;
#pragma unroll
        for (int cb = 0; cb < 4; ++cb)
#pragma unroll
            for (int i = 0; i < 4; ++i) ml = fmaxf(ml, sacc[cb][i]);
        ml = fmaxf(ml, __shfl_xor(ml, 16, 64));
        ml = fmaxf(ml, __shfl_xor(ml, 32, 64));
        float mnew  = fmaxf(mrun, ml);
        float alpha = __expf(mrun - mnew);
        float p[16];
        float rs = 0.f;
#pragma unroll
        for (int cb = 0; cb < 4; ++cb)
#pragma unroll
            for (int i = 0; i < 4; ++i) {
                float e = __expf(sacc[cb][i] - mnew);
                p[cb * 4 + i] = e;
                rs += e;
            }
        rs += __shfl_xor(rs, 16, 64);
        rs += __shfl_xor(rs, 32, 64);
        lrun = lrun * alpha + rs;
        mrun = mnew;

        {
            ushort_t* pw = &Ps[wv * 1152 + L * 72];
#pragma unroll
            for (int cb = 0; cb < 4; ++cb) {
                uint2 u;
                u.x = pack2bf(p[cb * 4 + 0], p[cb * 4 + 1]);
                u.y = pack2bf(p[cb * 4 + 2], p[cb * 4 + 3]);
                *(uint2*)&pw[cb * 16 + quad * 4] = u;
            }
        }
#pragma unroll
        for (int i = 0; i < 4; ++i) {
            float ai = __shfl(alpha, quad * 4 + i, 64);
            oacc[0][i] *= ai;
            oacc[1][i] *= ai;
        }
        __syncthreads();

#pragma unroll
        for (int ks = 0; ks < 2; ++ks) {
            short8 pf = *(const short8*)&Ps[wv * 1152 + L * 72 + ks * 32 + quad * 8];
#pragma unroll
            for (int db = 0; db < 2; ++db) {
                short8 vf = *(const short8*)&Vt[it * 2304 + (db * 16 + L) * 72 + ks * 32 + quad * 8];
                oacc[db] = __builtin_amdgcn_mfma_f32_16x16x32_bf16(pf, vf, oacc[db], 0, 0, 0);
            }
        }
    }

#pragma unroll
    for (int i = 0; i < 4; ++i) {
        float lq = __shfl(lrun, quad * 4 + i, 64);
        float li = 1.f / lq;
        int q = q0 + wv * 16 + quad * 4 + i;
        if (q < NQ) {
            ushort_t* op = attn_out + ((size_t)q * 4 + b) * 256 + h * 32 + L;
            op[0]  = (ushort_t)f2bf1(oacc[0][i] * li);
            op[16] = (ushort_t)f2bf1(oacc[1][i] * li);
        }
    }
}

// ---------------------------------------------------------------------------
// Plain 64x64-tile GEMM, bf16 A, bf16 W, fp32 C.
// ---------------------------------------------------------------------------
__global__ __launch_bounds__(256) void gemm16_f32(
    const ushort_t* __restrict__ A, const ushort_t* __restrict__ W,
    const float* __restrict__ bias, float* __restrict__ C,
    int M, int N, int K, int ldc)
{
    __shared__ ushort_t As[64 * GPAD];
    __shared__ ushort_t Ws[64 * GPAD];

    const int t  = threadIdx.x;
    const int m0 = blockIdx.x * 64;
    const int n0 = blockIdx.y * 64;
    const int trow = t >> 2;
    const int tk   = (t & 3) << 4;
    const int wv   = t >> 6;
    const int ln   = t & 63;
    const int L    = ln & 15;
    const int quad = ln >> 4;

    f32x4 acc[4] = {{0.f,0.f,0.f,0.f},{0.f,0.f,0.f,0.f},
                    {0.f,0.f,0.f,0.f},{0.f,0.f,0.f,0.f}};

    for (int k0 = 0; k0 < K; k0 += 64) {
        {
            int m = m0 + trow;
            uint4 a0 = make_uint4(0u,0u,0u,0u), a1 = make_uint4(0u,0u,0u,0u);
            if (m < M) {
                const ushort_t* ap = A + (size_t)m * K + k0 + tk;
                a0 = *(const uint4*)ap;
                a1 = *(const uint4*)(ap + 8);
            }
            *(uint4*)&As[trow * GPAD + tk + 0] = a0;
            *(uint4*)&As[trow * GPAD + tk + 8] = a1;
        }
        {
            int n = n0 + trow;
            const ushort_t* wp = W + (size_t)n * K + k0 + tk;
            *(uint4*)&Ws[trow * GPAD + tk + 0] = *(const uint4*)(wp + 0);
            *(uint4*)&Ws[trow * GPAD + tk + 8] = *(const uint4*)(wp + 8);
        }
        __syncthreads();
#pragma unroll
        for (int kh = 0; kh < 2; ++kh) {
            short8 af = *(const short8*)&As[(wv * 16 + L) * GPAD + kh * 32 + quad * 8];
#pragma unroll
            for (int cb = 0; cb < 4; ++cb) {
                short8 bf = *(const short8*)&Ws[(cb * 16 + L) * GPAD + kh * 32 + quad * 8];
                acc[cb] = __builtin_amdgcn_mfma_f32_16x16x32_bf16(af, bf, acc[cb], 0, 0, 0);
            }
        }
        __syncthreads();
    }
#pragma unroll
    for (int cb = 0; cb < 4; ++cb) {
        int col = n0 + cb * 16 + L;
        float bv = bias[col];
#pragma unroll
        for (int i = 0; i < 4; ++i) {
            int m = m0 + wv * 16 + quad * 4 + i;
            if (m < M)
                C[(size_t)m * ldc + col] = acc[cb][i] + bv;
        }
    }
}

// ---------------------------------------------------------------------------
// Residual + LayerNorm + optional bf16 out2(+pos). One block per row.
// ---------------------------------------------------------------------------
__global__ __launch_bounds__(256) void ln_resid16(
    const float* __restrict__ xa, const float* __restrict__ xb,
    const float* __restrict__ gam, const float* __restrict__ bet,
    float* __restrict__ out, const float* __restrict__ pos,
    ushort_t* __restrict__ out2)
{
    const int row = blockIdx.x;
    const int t = threadIdx.x;
    float x = xa[(size_t)row * D_MODEL + t] + xb[(size_t)row * D_MODEL + t];
    float s = x, s2 = x * x;
#pragma unroll
    for (int off = 32; off > 0; off >>= 1) {
        s  += __shfl_down(s, off, 64);
        s2 += __shfl_down(s2, off, 64);
    }
    __shared__ float rs[4], rs2[4];
    __shared__ float mean_s, rstd_s;
    int wid = t >> 6, lane = t & 63;
    if (lane == 0) { rs[wid] = s; rs2[wid] = s2; }
    __syncthreads();
    if (t == 0) {
        float S = rs[0] + rs[1] + rs[2] + rs[3];
        float S2 = rs2[0] + rs2[1] + rs2[2] + rs2[3];
        float mean = S * (1.f / 256.f);
        float var = S2 * (1.f / 256.f) - mean * mean;
        mean_s = mean;
        rstd_s = rsqrtf(var + 1e-5f);
    }
    __syncthreads();
    float y = (x - mean_s) * rstd_s * gam[t] + bet[t];
    out[(size_t)row * D_MODEL + t] = y;
    if (out2) {
        float o2 = y + (pos ? pos[(size_t)row * D_MODEL + t] : 0.f);
        out2[(size_t)row * D_MODEL + t] = (ushort_t)f2bf1(o2);
    }
}

// ---------------------------------------------------------------------------
// Fused offset + attention-weight GEMM (bf16 weights).
// ---------------------------------------------------------------------------
__global__ __launch_bounds__(256) void offaw16(
    const ushort_t* __restrict__ A,
    const ushort_t* __restrict__ off_wb, const float* __restrict__ off_b,
    const ushort_t* __restrict__ aw_wb, const float* __restrict__ aw_b,
    float* __restrict__ off_raw, float* __restrict__ aw_raw)
{
    __shared__ ushort_t As[64 * GPAD];
    __shared__ ushort_t Ws[64 * GPAD];

    const int t  = threadIdx.x;
    const int m0 = blockIdx.x * 64;
    const int by = blockIdx.y;
    const bool isaw = (by >= 4);
    const int n0 = isaw ? (by - 4) * 64 : by * 64;
    const ushort_t* W = isaw ? aw_wb : off_wb;
    const float* bs = isaw ? aw_b : off_b;
    float* C = isaw ? aw_raw : off_raw;
    const int ldc = isaw ? 128 : 256;

    const int trow = t >> 2;
    const int tk   = (t & 3) << 4;
    const int wv   = t >> 6;
    const int ln   = t & 63;
    const int L    = ln & 15;
    const int quad = ln >> 4;

    f32x4 acc[4] = {{0.f,0.f,0.f,0.f},{0.f,0.f,0.f,0.f},
                    {0.f,0.f,0.f,0.f},{0.f,0.f,0.f,0.f}};

    for (int k0 = 0; k0 < 256; k0 += 64) {
        {
            int m = m0 + trow;
            uint4 a0 = make_uint4(0u,0u,0u,0u), a1 = make_uint4(0u,0u,0u,0u);
            if (m < NROW) {
                const ushort_t* ap = A + (size_t)m * 256 + k0 + tk;
                a0 = *(const uint4*)ap;
                a1 = *(const uint4*)(ap + 8);
            }
            *(uint4*)&As[trow * GPAD + tk + 0] = a0;
            *(uint4*)&As[trow * GPAD + tk + 8] = a1;
        }
        {
            int n = n0 + trow;
            const ushort_t* wp = W + (size_t)n * 256 + k0 + tk;
            *(uint4*)&Ws[trow * GPAD + tk + 0] = *(const uint4*)(wp + 0);
            *(uint4*)&Ws[trow * GPAD + tk + 8] = *(const uint4*)(wp + 8);
        }
        __syncthreads();
#pragma unroll
        for (int kh = 0; kh < 2; ++kh) {
            short8 af = *(const short8*)&As[(wv * 16 + L) * GPAD + kh * 32 + quad * 8];
#pragma unroll
            for (int cb = 0; cb < 4; ++cb) {
                short8 bf = *(const short8*)&Ws[(cb * 16 + L) * GPAD + kh * 32 + quad * 8];
                acc[cb] = __builtin_amdgcn_mfma_f32_16x16x32_bf16(af, bf, acc[cb], 0, 0, 0);
            }
        }
        __syncthreads();
    }
#pragma unroll
    for (int cb = 0; cb < 4; ++cb) {
        int col = n0 + cb * 16 + L;
        float bv = bs[col];
#pragma unroll
        for (int i = 0; i < 4; ++i) {
            int m = m0 + wv * 16 + quad * 4 + i;
            if (m < NROW)
                C[(size_t)m * ldc + col] = acc[cb][i] + bv;
        }
    }
}

// ---------------------------------------------------------------------------
// Generic A-bf16, W-bf16 -> C-bf16 GEMM (FFN1 with ReLU).
// ---------------------------------------------------------------------------
__global__ __launch_bounds__(256) void gemm16_16(
    const ushort_t* __restrict__ A, const ushort_t* __restrict__ W,
    const float* __restrict__ bias, ushort_t* __restrict__ C,
    int M, int N, int K, int ldc, int relu)
{
    __shared__ ushort_t As[64 * GPAD];
    __shared__ ushort_t Ws[64 * GPAD];

    const int t  = threadIdx.x;
    const int m0 = blockIdx.x * 64;
    const int n0 = blockIdx.y * 64;
    const int trow = t >> 2;
    const int tk   = (t & 3) << 4;
    const int wv   = t >> 6;
    const int ln   = t & 63;
    const int L    = ln & 15;
    const int quad = ln >> 4;

    f32x4 acc[4] = {{0.f,0.f,0.f,0.f},{0.f,0.f,0.f,0.f},
                    {0.f,0.f,0.f,0.f},{0.f,0.f,0.f,0.f}};

    for (int k0 = 0; k0 < K; k0 += 64) {
        {
            int m = m0 + trow;
            uint4 a0 = make_uint4(0u,0u,0u,0u), a1 = make_uint4(0u,0u,0u,0u);
            if (m < M) {
                const ushort_t* ap = A + (size_t)m * K + k0 + tk;
                a0 = *(const uint4*)ap;
                a1 = *(const uint4*)(ap + 8);
            }
            *(uint4*)&As[trow * GPAD + tk + 0] = a0;
            *(uint4*)&As[trow * GPAD + tk + 8] = a1;
        }
        {
            int n = n0 + trow;
            const ushort_t* wp = W + (size_t)n * K + k0 + tk;
            *(uint4*)&Ws[trow * GPAD + tk + 0] = *(const uint4*)(wp + 0);
            *(uint4*)&Ws[trow * GPAD + tk + 8] = *(const uint4*)(wp + 8);
        }
        __syncthreads();
#pragma unroll
        for (int kh = 0; kh < 2; ++kh) {
            short8 af = *(const short8*)&As[(wv * 16 + L) * GPAD + kh * 32 + quad * 8];
#pragma unroll
            for (int cb = 0; cb < 4; ++cb) {
                short8 bf = *(const short8*)&Ws[(cb * 16 + L) * GPAD + kh * 32 + quad * 8];
                acc[cb] = __builtin_amdgcn_mfma_f32_16x16x32_bf16(af, bf, acc[cb], 0, 0, 0);
            }
        }
        __syncthreads();
    }
#pragma unroll
    for (int cb = 0; cb < 4; ++cb) {
        int col = n0 + cb * 16 + L;
        float bv = bias[col];
#pragma unroll
        for (int i = 0; i < 4; ++i) {
            int m = m0 + wv * 16 + quad * 4 + i;
            if (m < M) {
                float o = acc[cb][i] + bv;
                if (relu) o = fmaxf(o, 0.f);
                C[(size_t)m * ldc + col] = (ushort_t)f2bf1(o);
            }
        }
    }
}

// ---------------------------------------------------------------------------
// Multi-scale deformable sampling (unchanged).
// ---------------------------------------------------------------------------
__global__ __launch_bounds__(256) void msdeform16(
    const float* __restrict__ off_raw, const float* __restrict__ aw_raw,
    const float* __restrict__ refp, const ushort_t* __restrict__ value,
    ushort_t* __restrict__ out)
{
    const int row = blockIdx.x;   // q*4+b
    const int b = row & 3;
    const int t = threadIdx.x;

    __shared__ float aw_s[8][17];
    __shared__ float px_s[8][16];
    __shared__ float py_s[8][16];

    const int Hs[4]  = {92, 46, 23, 12};
    const int Wd[4]  = {92, 46, 23, 12};
    const int S0_[4] = {0, 8464, 10580, 11109};

    if (t < 128) {
        int hh = t >> 4, lp = t & 15, l = lp >> 2;
        float ox = off_raw[(size_t)row * 256 + hh * 32 + lp * 2 + 0];
        float oy = off_raw[(size_t)row * 256 + hh * 32 + lp * 2 + 1];
        float rx = refp[((size_t)row * 4 + l) * 2 + 0];
        float ry = refp[((size_t)row * 4 + l) * 2 + 1];
        px_s[hh][lp] = rx * (float)Wd[l] + ox - 0.5f;
        py_s[hh][lp] = ry * (float)Hs[l] + oy - 0.5f;
    }
    if (t < 8) {
        int hh = t;
        float v[16];
        float m = -1e30f;
#pragma unroll
        for (int j = 0; j < 16; ++j) {
            v[j] = aw_raw[(size_t)row * 128 + hh * 16 + j];
            m = fmaxf(m, v[j]);
        }
        float ssum = 0.f;
#pragma unroll
        for (int j = 0; j < 16; ++j) { v[j] = __expf(v[j] - m); ssum += v[j]; }
        float inv = 1.f / ssum;
#pragma unroll
        for (int j = 0; j < 16; ++j) aw_s[hh][j] = v[j] * inv;
    }
    __syncthreads();

    const int h = t >> 5, d = t & 31;
    const ushort_t* vb = value + (size_t)b * 256 + h * 32 + d;
    float acc = 0.f;
#pragma unroll
    for (int l = 0; l < 4; ++l) {
        const int H = Hs[l], W = Wd[l], base = S0_[l];
#pragma unroll
        for (int p = 0; p < 4; ++p) {
            const int lp = l * 4 + p;
            float px = px_s[h][lp], py = py_s[h][lp];
            float x0f = floorf(px), y0f = floorf(py);
            int x0 = (int)x0f, y0 = (int)y0f;
            float wx = px - x0f, wy = py - y0f;
            float sv = 0.f;
#pragma unroll
            for (int dy = 0; dy < 2; ++dy) {
#pragma unroll
                for (int dx = 0; dx < 2; ++dx) {
                    int xi = x0 + dx, yi = y0 + dy;
                    float flag = (xi >= 0 && xi < W && yi >= 0 && yi < H) ? 1.f : 0.f;
                    int xc = xi < 0 ? 0 : (xi >= W ? W - 1 : xi);
                    int yc = yi < 0 ? 0 : (yi >= H ? H - 1 : yi);
                    float wgt = (dx ? wx : 1.f - wx) * (dy ? wy : 1.f - wy);
                    float gv = bf2f(vb[(size_t)(base + yc * W + xc) * 1024]);
                    sv = fmaf(wgt * flag, gv, sv);
                }
            }
            acc = fmaf(aw_s[h][lp], sv, acc);
        }
    }
    out[(size_t)row * 256 + h * 32 + d] = (ushort_t)f2bf1(acc);
}

// ---------------------------------------------------------------------------
extern "C" void kernel_launch(void* const* d_in, const int* in_sizes, int n_in,
                              void* d_out, int out_size, void* d_ws, size_t ws_size,
                              hipStream_t stream)
{
    const float* tgt    = (const float*)d_in[0];
    const float* qpos   = (const float*)d_in[1];
    const float* refp   = (const float*)d_in[2];
    const float* mem    = (const float*)d_in[3];
    const float* in_w   = (const float*)d_in[6];
    const float* in_b   = (const float*)d_in[7];
    const float* outp_w = (const float*)d_in[8];
    const float* outp_b = (const float*)d_in[9];
    const float* off_w  = (const float*)d_in[10];
    const float* off_b  = (const float*)d_in[11];
    const float* aw_w   = (const float*)d_in[12];
    const float* aw_b   = (const float*)d_in[13];
    const float* vp_w   = (const float*)d_in[14];
    const float* vp_b   = (const float*)d_in[15];
    const float* op_w   = (const float*)d_in[16];
    const float* op_b   = (const float*)d_in[17];
    const float* ln1g   = (const float*)d_in[18];
    const float* ln1b   = (const float*)d_in[19];
    const float* ln2g   = (const float*)d_in[20];
    const float* ln2b   = (const float*)d_in[21];
    const float* ln3g   = (const float*)d_in[22];
    const float* ln3b   = (const float*)d_in[23];
    const float* l1w    = (const float*)d_in[24];
    const float* l1b    = (const float*)d_in[25];
    const float* l2w    = (const float*)d_in[26];
    const float* l2b    = (const float*)d_in[27];
    float* out = (float*)d_out;
    float* ws  = (float*)d_ws;

    // workspace layout (float units)
    ushort_t* qkv16    = (ushort_t*)ws;                 // 691200 floats
    ushort_t* att16    = (ushort_t*)(ws + 691200);      // 230400
    float*    tmp      = ws + 921600;                   // 921600
    float*    tgt_a    = ws + 1843200;                  // 921600
    ushort_t* xca16    = (ushort_t*)(ws + 2764800);     // 230400
    float*    off_raw  = ws + 2995200;                  // 921600
    float*    aw_raw   = ws + 3916800;                  // 460800
    ushort_t* att2_16  = (ushort_t*)(ws + 4377600);     // 230400
    float*    tgt_b    = ws + 4608000;                  // 921600
    ushort_t* tgtb16   = (ushort_t*)(ws + 5529600);     // 230400
    ushort_t* value16  = (ushort_t*)(ws + 5760000);     // 5761536
    ushort_t* hidden16 = (ushort_t*)(ws + 11521536);    // 1843200
    ushort_t* wb       = (ushort_t*)(ws + 13364736);    // 507904 (bf16 weights)

    const ushort_t* in_wb   = wb + WB_IN;
    const ushort_t* vp_wb   = wb + WB_VP;
    const ushort_t* outp_wb = wb + WB_OUTP;
    const ushort_t* off_wb  = wb + WB_OFF;
    const ushort_t* aw_wb   = wb + WB_AW;
    const ushort_t* op_wb   = wb + WB_OP;
    const ushort_t* l1_wb   = wb + WB_L1;
    const ushort_t* l2_wb   = wb + WB_L2;

    dim3 b256(256);

    // 0. one-shot weight conversion fp32 -> bf16
    hipLaunchKernelGGL(cvt_weights, dim3(496), b256, 0, stream,
                       in_w, vp_w, outp_w, off_w, aw_w, op_w, l1w, l2w, wb);
    // 1. qkv + value projection (vproj N-split for occupancy)
    hipLaunchKernelGGL(proj_fused, dim3(2092), b256, 0, stream,
                       tgt, qpos, in_wb, in_b, mem, vp_wb, vp_b, qkv16, value16);
    // 2. flash self-attention
    hipLaunchKernelGGL(sa_flash16, dim3(15, 32), b256, 0, stream, qkv16, att16);
    // 3. out-proj -> tmp (fp32)
    hipLaunchKernelGGL(gemm16_f32, dim3(57, 4), b256, 0, stream,
                       att16, outp_wb, outp_b, tmp, NROW, 256, 256, 256);
    // 4. LN2: tgt_a = LN(tgt + tmp); xca16 = bf16(tgt_a + qpos)
    hipLaunchKernelGGL(ln_resid16, dim3(3600), b256, 0, stream,
                       tgt, tmp, ln2g, ln2b, tgt_a, qpos, xca16);
    // 5. fused sampling-offset + attention-weight GEMMs
    hipLaunchKernelGGL(offaw16, dim3(57, 6), b256, 0, stream,
                       xca16, off_wb, off_b, aw_wb, aw_b, off_raw, aw_raw);
    // 6. deformable sampling (bf16 out)
    hipLaunchKernelGGL(msdeform16, dim3(3600), b256, 0, stream,
                       off_raw, aw_raw, refp, value16, att2_16);
    // 7. oproj -> tmp
    hipLaunchKernelGGL(gemm16_f32, dim3(57, 4), b256, 0, stream,
                       att2_16, op_wb, op_b, tmp, NROW, 256, 256, 256);
    // 8. LN1: tgt_b = LN(tgt_a + tmp); tgtb16 = bf16(tgt_b)
    hipLaunchKernelGGL(ln_resid16, dim3(3600), b256, 0, stream,
                       tgt_a, tmp, ln1g, ln1b, tgt_b, (const float*)nullptr, tgtb16);
    // 9. FFN1 + ReLU (bf16 out)
    hipLaunchKernelGGL(gemm16_16, dim3(57, 16), b256, 0, stream,
                       tgtb16, l1_wb, l1b, hidden16, NROW, 1024, 256, 1024, 1);
    // 10. FFN2 -> tmp
    hipLaunchKernelGGL(gemm16_f32, dim3(57, 4), b256, 0, stream,
                       hidden16, l2_wb, l2b, tmp, NROW, 256, 1024, 256);
    // 11. LN3 -> d_out
    hipLaunchKernelGGL(ln_resid16, dim3(3600), b256, 0, stream,
                       tgt_b, tmp, ln3g, ln3b, out, (const float*)nullptr, (ushort_t*)nullptr);
}